// Round 15
// baseline (935.902 us; speedup 1.0000x reference)
//
#include <hip/hip_runtime.h>
#include <math.h>

// FireflyVQ R15: R12 numerics (bit-exact, realization-locked code path).
// gemm_down: 128x128 tile restored (R12's best) but with 8 waves/block
// (512 thr) -> 16 waves/CU (was 8). Per-output FP chains bit-identical.
// e0f full-chip BN=64 (R14). Up path x = Wx @ Q + bx. RVQ unchanged.

using u16 = unsigned short;
typedef __attribute__((ext_vector_type(8))) short bf16x8;
typedef __attribute__((ext_vector_type(8))) u16 su16x8;
typedef __attribute__((ext_vector_type(4))) float f32x4;

constexpr int NQ = 9, CBS = 1024, CBD = 8;
constexpr int TQ = 2048;
constexpr int NTOK = 16384;
constexpr int APS = 1048576;   // u16 per W_d split plane (512*2048)
#define EPSN 1e-12f

// ---- ws layout (float offsets), ~58.7 MB (R12's)
constexpr size_t OFF_X2    = 0;                  // [8][512][2048] fp32
constexpr size_t OFF_E0T   = 8388608;            // [16384][72]
constexpr size_t OFF_Q     = 9568256;            // [72][16384]
constexpr size_t OFF_WD    = 10747904;           // W_d [512][2048] fp32
constexpr size_t OFF_WDP   = 11796480;           // 3 u16 planes of W_d (1,572,864 fl)
constexpr size_t OFF_WEFF  = 13369344;           // W_eff [2048][512] fp32
constexpr size_t OFF_WX    = 14417920;           // Wx [2048][80] fp32 (col72 = W_eff·bsum)
constexpr size_t OFF_WINN  = 14581760;           // [72][512]
constexpr size_t OFF_WOUTS = 14618624;           // WoutS2 [512][80] (col72=bsum, 73..79=0)
constexpr size_t OFF_CBS   = 14659584;           // [9][2][1024]
constexpr size_t OFF_PT    = 14678016;           // 2340
constexpr size_t OFF_BEFF  = 14680356;           // 72
constexpr size_t OFF_BSUM  = 14680428;           // 512
constexpr size_t OFF_BD    = 14680940;           // 512
constexpr size_t OFF_BUP   = 14681452;           // [512][2]
constexpr size_t OFF_LOSS  = 14682476;           // 1024

// ---------------- prep_small1 (R12 verbatim) ----------------
__global__ void prep_small1(const float* __restrict__ in_v, const float* __restrict__ in_g,
                            const float* __restrict__ out_v, const float* __restrict__ out_g,
                            const float* __restrict__ out_b, const float* __restrict__ codebooks,
                            const float* __restrict__ down_w, const float* __restrict__ down_b,
                            const float* __restrict__ up_w, const float* __restrict__ up_b,
                            float* __restrict__ ws) {
  int bid = blockIdx.x, tid = threadIdx.x;
  int wid4 = tid >> 6, lane = tid & 63;
  if (bid < 18) {  // WinN rows
    int wid = bid * 4 + wid4;
    if (wid < 72) {
      const float* v = in_v + (size_t)wid * 512;
      float ss = 0.f;
      for (int c = lane; c < 512; c += 64) ss += v[c] * v[c];
      #pragma unroll
      for (int o = 32; o; o >>= 1) ss += __shfl_xor(ss, o);
      float sc = in_g[wid] / sqrtf(ss);
      float* dst = ws + OFF_WINN + (size_t)wid * 512;
      for (int c = lane; c < 512; c += 64) dst[c] = v[c] * sc;
    }
  } else if (bid < 36) {  // WoutS2 [c][80], cols 0..71
    int r = (bid - 18) * 256 + tid;
    if (r < 4608) {
      int i = r >> 9, c = r & 511;
      const float* v = out_v + (size_t)r * 8;
      float ss = 0.f;
      #pragma unroll
      for (int d = 0; d < 8; d++) ss += v[d] * v[d];
      float sc = out_g[r] / sqrtf(ss);
      float* dst = ws + OFF_WOUTS + (size_t)c * 80 + i * 8;
      #pragma unroll
      for (int d = 0; d < 8; d++) dst[d] = v[d] * sc;
    }
  } else if (bid < 72) {  // codebook scalars
    int r = (bid - 36) * 256 + tid;
    if (r < 9216) {
      int i = r >> 10, j = r & 1023;
      const float* v = codebooks + (size_t)r * 8;
      float ss = 0.f;
      #pragma unroll
      for (int d = 0; d < 8; d++) ss += v[d] * v[d];
      float nm = fmaxf(sqrtf(ss), EPSN);
      float nsq = 0.f;
      #pragma unroll
      for (int d = 0; d < 8; d++) { float cn = v[d] / nm; nsq += cn * cn; }
      ws[OFF_CBS + ((size_t)i * 2 + 0) * 1024 + j] = 2.0f / nm;
      ws[OFF_CBS + ((size_t)i * 2 + 1) * 1024 + j] = nsq;
    }
  } else if (bid < 74) {  // bsum + WoutS2 col 72..79
    int c = (bid - 72) * 256 + tid;
    if (c < 512) {
      float s = 0.f;
      #pragma unroll
      for (int j = 0; j < 9; j++) s += out_b[j * 512 + c];
      ws[OFF_BSUM + c] = s;
      ws[OFF_WOUTS + (size_t)c * 80 + 72] = s;
      #pragma unroll
      for (int d = 73; d < 80; d++) ws[OFF_WOUTS + (size_t)c * 80 + d] = 0.f;
    }
  } else if (bid < 202) {  // b_d[o]
    int o = (bid - 74) * 4 + wid4;
    float s = 0.f;
    for (int m = lane; m < 512; m += 64) {
      float w0 = down_w[524288 + (size_t)o * 1024 + m * 2];
      float w1 = down_w[524288 + (size_t)o * 1024 + m * 2 + 1];
      s += (w0 + w1) * down_b[m];
    }
    #pragma unroll
    for (int off = 32; off; off >>= 1) s += __shfl_xor(s, off);
    if (lane == 0) ws[OFF_BD + o] = s + down_b[512 + o];
  } else {  // bup[c][j2]
    int gw = (bid - 202) * 4 + wid4;
    int c = gw >> 1, j2 = gw & 1;
    float s = 0.f;
    for (int m = lane; m < 512; m += 64)
      s += up_w[524288 + (size_t)m * 1024 + c * 2 + j2] * up_b[m];
    #pragma unroll
    for (int off = 32; off; off >>= 1) s += __shfl_xor(s, off);
    if (lane == 0) ws[OFF_BUP + gw] = s + up_b[512 + c];
  }
}

// ---------------- prep2 (R12 verbatim) ----------------
__global__ void prep2(const float* __restrict__ in_b, const float* __restrict__ out_b,
                      float* __restrict__ ws) {
  int gw = blockIdx.x * 4 + (threadIdx.x >> 6), lane = threadIdx.x & 63;
  const float* WinN = ws + OFF_WINN;
  const float* WoutS = ws + OFF_WOUTS;
  if (gw < 2304) {
    int tri = gw >> 6, dd = gw & 63;
    int ip = 1;
    while (tri >= ip * (ip + 1) / 2) ip++;
    int i = tri - ip * (ip - 1) / 2;
    int d = dd >> 3, dp = dd & 7;
    const float* a = WinN + (size_t)(ip * 8 + d) * 512;
    float s = 0.f;
    for (int c = lane; c < 512; c += 64) s += a[c] * WoutS[(size_t)c * 80 + i * 8 + dp];
    #pragma unroll
    for (int o = 32; o; o >>= 1) s += __shfl_xor(s, o);
    if (lane == 0) ws[OFF_PT + (size_t)tri * 65 + dd] = s;
  } else if (gw < 2376) {
    int r = gw - 2304;
    int i = r >> 3;
    const float* a = WinN + (size_t)r * 512;
    float s = 0.f;
    for (int c = lane; c < 512; c += 64) {
      float ob = 0.f;
      for (int j = 0; j < i; j++) ob += out_b[j * 512 + c];
      s += a[c] * ob;
    }
    #pragma unroll
    for (int o = 32; o; o >>= 1) s += __shfl_xor(s, o);
    if (lane == 0) ws[OFF_BEFF + r] = in_b[r] - s;
  }
}

// ---------------- smallmm (R12 verbatim) ----------------
template <int WHICH>
__global__ __launch_bounds__(256) void smallmm(const float* __restrict__ src,
                                               float* __restrict__ outp) {
  __shared__ float As[32][68];
  __shared__ float Bs[32][68];
  const int tid = threadIdx.x;
  const int tx = tid & 15, ty = tid >> 4;
  const int b0 = blockIdx.x * 64, a0 = blockIdx.y * 64, j = blockIdx.z;
  const int jh = j >> 1, jl = j & 1;
  float acc[4][4];
  #pragma unroll
  for (int i = 0; i < 4; i++)
    #pragma unroll
    for (int k = 0; k < 4; k++) acc[i][k] = 0.f;

  for (int k0 = 0; k0 < 512; k0 += 32) {
    #pragma unroll
    for (int rep = 0; rep < 8; rep++) {
      int f = tid + rep * 256;
      int aa = f >> 5, mm = f & 31;
      size_t ai;
      if constexpr (WHICH == 0) ai = 524288 + (size_t)(a0 + aa) * 1024 + (k0 + mm) * 2 + jh;
      else                      ai = 524288 + (size_t)(k0 + mm) * 1024 + (a0 + aa) * 2 + jl;
      As[mm][aa] = src[ai];
      int mm2 = f >> 6, bb = f & 63;
      size_t bi;
      if constexpr (WHICH == 0) bi = (size_t)(k0 + mm2) * 1024 + (b0 + bb) * 2 + jl;
      else                      bi = (size_t)(b0 + bb) * 1024 + (k0 + mm2) * 2 + jh;
      Bs[mm2][bb] = src[bi];
    }
    __syncthreads();
    #pragma unroll
    for (int kk = 0; kk < 32; kk++) {
      float av[4], bv[4];
      #pragma unroll
      for (int i = 0; i < 4; i++) av[i] = As[kk][ty * 4 + i];
      #pragma unroll
      for (int i = 0; i < 4; i++) bv[i] = Bs[kk][tx * 4 + i];
      #pragma unroll
      for (int i = 0; i < 4; i++)
        #pragma unroll
        for (int k = 0; k < 4; k++) acc[i][k] = fmaf(av[i], bv[k], acc[i][k]);
    }
    __syncthreads();
  }
  #pragma unroll
  for (int i = 0; i < 4; i++) {
    int a = a0 + ty * 4 + i;
    #pragma unroll
    for (int k = 0; k < 4; k++) {
      int b = b0 + tx * 4 + k;
      if constexpr (WHICH == 0) outp[(size_t)a * 2048 + b * 4 + j] = acc[i][k];
      else                      outp[((size_t)a * 4 + j) * 512 + b] = acc[i][k];
    }
  }
}

// ---------------- prep_wdsplit (R12 verbatim) ----------------
__global__ void prep_wdsplit(const float* __restrict__ wd, u16* __restrict__ wdp) {
  int idx = blockIdx.x * 256 + threadIdx.x;
  float v = wd[idx];
  unsigned u = __float_as_uint(v);
  wdp[idx] = (u16)(u >> 16);
  float r = v - __uint_as_float(u & 0xFFFF0000u);
  unsigned ur = __float_as_uint(r);
  wdp[APS + idx] = (u16)(ur >> 16);
  float r2 = r - __uint_as_float(ur & 0xFFFF0000u);
  wdp[2 * APS + idx] = (u16)(__float_as_uint(r2) >> 16);
}

// ---------------- prep_wx (R12 verbatim) ----------------
__global__ __launch_bounds__(256) void prep_wx(const float* __restrict__ weff,
                                               const float* __restrict__ wouts,
                                               float* __restrict__ wx) {
  __shared__ float Wes[16][512];
  __shared__ float WSs[64][80];
  const int tid = threadIdx.x;
  const int m0 = blockIdx.x * 16;
  #pragma unroll
  for (int rep = 0; rep < 32; rep++) {
    int f = tid + rep * 256;
    Wes[f >> 9][f & 511] = weff[(size_t)(m0 + (f >> 9)) * 512 + (f & 511)];
  }
  const int rowq = tid >> 4, rq = tid & 15;
  float accs[5] = {0.f, 0.f, 0.f, 0.f, 0.f};
  for (int k0 = 0; k0 < 512; k0 += 64) {
    __syncthreads();
    #pragma unroll
    for (int rep = 0; rep < 20; rep++) {
      int f = tid + rep * 256;
      int kk = f / 80, col = f % 80;
      WSs[kk][col] = wouts[(size_t)(k0 + kk) * 80 + col];
    }
    __syncthreads();
    #pragma unroll 4
    for (int kk = 0; kk < 64; kk++) {
      float we = Wes[rowq][k0 + kk];
      #pragma unroll
      for (int s = 0; s < 5; s++) accs[s] = fmaf(we, WSs[kk][rq + 16 * s], accs[s]);
    }
  }
  #pragma unroll
  for (int s = 0; s < 5; s++) {
    int r = rq + 16 * s;
    if (r < 73) wx[(size_t)(m0 + rowq) * 80 + r] = accs[s];
  }
  if (tid < 112) {
    int row = tid / 7, col = 73 + tid % 7;
    wx[(size_t)(m0 + row) * 80 + col] = 0.f;
  }
}

// ---------------- gemm_down: 128x128 tile, 8 waves (512 thr) ----------------
// Grid (128, 4) = 512 blocks; 2 blocks/CU x 8 waves = 16 waves/CU.
// Waves 2m x 4n, each 64x32 (4x2 frags). Same splits / K order / 6-MFMA order
// as R12 -> per-output FP chains bit-identical.
__global__ __launch_bounds__(512) void gemm_down(const u16* __restrict__ Ap,
                                                 const float* __restrict__ z,
                                                 const float* __restrict__ bias,
                                                 float* __restrict__ Out) {
  constexpr int NS = 3, K = 2048;
  __shared__ u16 Bp[2][NS][128][32];
  const int tid = threadIdx.x;
  const int w = tid >> 6, l = tid & 63;
  const int g = l >> 4, li = l & 15;
  const int wr = w >> 2, wc = w & 3;
  const int n0 = blockIdx.x * 128, m0 = blockIdx.y * 128;
  const int nn = tid & 127, kq = tid >> 7;   // row-owner nn, k-quarter kq (8 elems)
  const int bb = n0 >> 11;
  const int tb = (n0 & 2047) + nn;

  f32x4 acc[4][2];
  #pragma unroll
  for (int a = 0; a < 4; a++)
    #pragma unroll
    for (int b = 0; b < 2; b++) acc[a][b] = (f32x4){0.f, 0.f, 0.f, 0.f};

  float pvA[8], pvB[8];

#define LOADB(PV, K0)                                                           \
  {                                                                             \
    int c0_ = ((K0) >> 2) + kq * 2;                                             \
    _Pragma("unroll")                                                           \
    for (int cc_ = 0; cc_ < 2; ++cc_)                                           \
      *(float4*)&PV[4 * cc_] =                                                  \
          *(const float4*)(z + ((size_t)(bb * 512 + c0_ + cc_) << 13) + 4 * tb);\
  }

  const int sw = (nn >> 1) & 3;
  const int cw = (kq ^ sw) << 3;

#define STAGE(BUF, PV)                                                          \
  {                                                                             \
    su16x8 pa_[NS];                                                             \
    _Pragma("unroll")                                                           \
    for (int j_ = 0; j_ < 8; ++j_) {                                            \
      float v_ = PV[j_];                                                        \
      unsigned u_ = __float_as_uint(v_);                                        \
      pa_[0][j_] = (u16)(u_ >> 16);                                             \
      float r_ = v_ - __uint_as_float(u_ & 0xFFFF0000u);                        \
      unsigned ur_ = __float_as_uint(r_);                                       \
      pa_[1][j_] = (u16)(ur_ >> 16);                                            \
      float r2_ = r_ - __uint_as_float(ur_ & 0xFFFF0000u);                      \
      pa_[2][j_] = (u16)(__float_as_uint(r2_) >> 16);                           \
    }                                                                           \
    _Pragma("unroll")                                                           \
    for (int p_ = 0; p_ < NS; ++p_)                                             \
      *(su16x8*)&Bp[BUF][p_][nn][cw] = pa_[p_];                                 \
  }

#define COMPUTE(BUF, K0)                                                        \
  {                                                                             \
    bf16x8 bfr_[2][NS];                                                         \
    _Pragma("unroll")                                                           \
    for (int fn_ = 0; fn_ < 2; ++fn_) {                                         \
      int row_ = wc * 32 + fn_ * 16 + li;                                       \
      int cs_ = ((g ^ ((row_ >> 1) & 3)) << 3);                                 \
      _Pragma("unroll")                                                         \
      for (int q_ = 0; q_ < NS; ++q_)                                           \
        bfr_[fn_][q_] = *(const bf16x8*)&Bp[BUF][q_][row_][cs_];                \
    }                                                                           \
    const u16* arow_ = Ap + (size_t)(m0 + wr * 64 + li) * K + (K0) + g * 8;     \
    _Pragma("unroll")                                                           \
    for (int fm_ = 0; fm_ < 4; ++fm_) {                                         \
      bf16x8 afr_[NS];                                                          \
      _Pragma("unroll")                                                         \
      for (int p_ = 0; p_ < NS; ++p_)                                           \
        afr_[p_] = *(const bf16x8*)(arow_ + (size_t)p_ * APS + (size_t)fm_ * 16 * K); \
      _Pragma("unroll")                                                         \
      for (int fn_ = 0; fn_ < 2; ++fn_) {                                       \
        f32x4 a_ = acc[fm_][fn_];                                               \
        a_ = __builtin_amdgcn_mfma_f32_16x16x32_bf16(afr_[2], bfr_[fn_][0], a_, 0, 0, 0); \
        a_ = __builtin_amdgcn_mfma_f32_16x16x32_bf16(afr_[1], bfr_[fn_][1], a_, 0, 0, 0); \
        a_ = __builtin_amdgcn_mfma_f32_16x16x32_bf16(afr_[0], bfr_[fn_][2], a_, 0, 0, 0); \
        a_ = __builtin_amdgcn_mfma_f32_16x16x32_bf16(afr_[1], bfr_[fn_][0], a_, 0, 0, 0); \
        a_ = __builtin_amdgcn_mfma_f32_16x16x32_bf16(afr_[0], bfr_[fn_][1], a_, 0, 0, 0); \
        a_ = __builtin_amdgcn_mfma_f32_16x16x32_bf16(afr_[0], bfr_[fn_][0], a_, 0, 0, 0); \
        acc[fm_][fn_] = a_;                                                     \
      }                                                                         \
    }                                                                           \
  }

  LOADB(pvA, 0)
  LOADB(pvB, 32)
  STAGE(0, pvA)
  LOADB(pvA, 64)
  __syncthreads();

  for (int k0 = 0; k0 < K; k0 += 64) {
    STAGE(1, pvB)
    if (k0 + 96 < K) { LOADB(pvB, k0 + 96) }
    COMPUTE(0, k0)
    __syncthreads();
    if (k0 + 64 < K) { STAGE(0, pvA) }
    if (k0 + 128 < K) { LOADB(pvA, k0 + 128) }
    COMPUTE(1, k0 + 32)
    __syncthreads();
  }
#undef LOADB
#undef STAGE
#undef COMPUTE

  const int mb = m0 + wr * 64 + g * 4;
  const int nb = n0 + wc * 32 + li;
  #pragma unroll
  for (int fn = 0; fn < 2; ++fn) {
    int n = nb + fn * 16;
    int b = n >> 11, t = n & 2047;
    #pragma unroll
    for (int fm = 0; fm < 4; ++fm)
      #pragma unroll
      for (int r = 0; r < 4; ++r) {
        int o = mb + fm * 16 + r;
        Out[((size_t)((b << 9) + o)) * 2048 + t] = acc[fm][fn][r] + bias[o];
      }
  }
}

// ---------------- gemm_e0f (R14 verbatim): e0t = WinN @ x2, BN=64 ----------------
__global__ __launch_bounds__(256) void gemm_e0f(const float* __restrict__ A,
                                                const float* __restrict__ Bsrc,
                                                float* __restrict__ e0t) {
  constexpr int M = 72, K = 512, Tt = 2048;
  __shared__ float As[16][132];
  __shared__ float Bs[16][68];
  int tid = threadIdx.x;
  int tx = tid & 7, ty = tid >> 3;
  int n0 = blockIdx.x * 64;
  int b = n0 / Tt, t0 = n0 % Tt;
  float acc[4][8];
  #pragma unroll
  for (int i = 0; i < 4; i++)
    #pragma unroll
    for (int j = 0; j < 8; j++) acc[i][j] = 0.f;

  for (int k0 = 0; k0 < K; k0 += 16) {
    #pragma unroll
    for (int rep = 0; rep < 2; rep++) {
      int f = tid + rep * 256;
      int row = f >> 2, c4 = (f & 3) << 2;
      int m = row, k = k0 + c4;
      float4 v = make_float4(0.f, 0.f, 0.f, 0.f);
      if (m < M) v = *(const float4*)(A + (size_t)m * K + k);
      As[c4 + 0][row] = v.x; As[c4 + 1][row] = v.y;
      As[c4 + 2][row] = v.z; As[c4 + 3][row] = v.w;
    }
    {
      int kk = tid >> 4, n4 = (tid & 15) << 2;
      float4 v = *(const float4*)(Bsrc + ((size_t)(b * K + k0 + kk)) * Tt + t0 + n4);
      *(float4*)&Bs[kk][n4] = v;
    }
    __syncthreads();
    #pragma unroll
    for (int kk = 0; kk < 16; kk++) {
      float a[4], bb[8];
      #pragma unroll
      for (int i = 0; i < 4; i++) a[i] = As[kk][ty * 4 + i];
      *(float4*)&bb[0] = *(float4*)&Bs[kk][tx * 8];
      *(float4*)&bb[4] = *(float4*)&Bs[kk][tx * 8 + 4];
      #pragma unroll
      for (int i = 0; i < 4; i++)
        #pragma unroll
        for (int j = 0; j < 8; j++) acc[i][j] = fmaf(a[i], bb[j], acc[i][j]);
    }
    __syncthreads();
  }
  #pragma unroll
  for (int j = 0; j < 8; j++) {
    int n = n0 + tx * 8 + j;
    #pragma unroll
    for (int i = 0; i < 4; i++) {
      int m = ty * 4 + i;
      if (m < M) e0t[(size_t)n * M + m] = acc[i][j];
    }
  }
}

// ---------------- xfin (R12 verbatim) ----------------
__global__ __launch_bounds__(256) void xfin(const float* __restrict__ wx,
                                            const float* __restrict__ Q,
                                            const float* __restrict__ bup,
                                            float* __restrict__ xout) {
  __shared__ float Wxs[128][80];
  __shared__ float Qs[128][80];
  const int tid = threadIdx.x;
  const int n0 = blockIdx.x * 128, m0 = blockIdx.y * 128;
  #pragma unroll
  for (int rep = 0; rep < 10; rep++) {
    int f = tid + rep * 256;
    *(float4*)&Wxs[0][f * 4] = *(const float4*)(wx + (size_t)m0 * 80 + f * 4);
  }
  {
    int nn = tid & 127, r0 = tid >> 7;
    for (int r = r0; r < 72; r += 2)
      Qs[nn][r] = Q[(size_t)r * 16384 + n0 + nn];
  }
  __syncthreads();

  const int txn = tid & 15, tym = tid >> 4;
  float acc[8][8];
  #pragma unroll
  for (int i = 0; i < 8; i++)
    #pragma unroll
    for (int j = 0; j < 8; j++) acc[i][j] = 0.f;

  #pragma unroll 2
  for (int r4 = 0; r4 < 18; r4++) {
    float4 wv[8], qv[8];
    #pragma unroll
    for (int i = 0; i < 8; i++) wv[i] = *(const float4*)&Wxs[tym * 8 + i][r4 * 4];
    #pragma unroll
    for (int j = 0; j < 8; j++) qv[j] = *(const float4*)&Qs[txn * 8 + j][r4 * 4];
    #pragma unroll
    for (int i = 0; i < 8; i++)
      #pragma unroll
      for (int j = 0; j < 8; j++) {
        acc[i][j] = fmaf(wv[i].x, qv[j].x, acc[i][j]);
        acc[i][j] = fmaf(wv[i].y, qv[j].y, acc[i][j]);
        acc[i][j] = fmaf(wv[i].z, qv[j].z, acc[i][j]);
        acc[i][j] = fmaf(wv[i].w, qv[j].w, acc[i][j]);
      }
  }

  float bxv[8];
  #pragma unroll
  for (int mi = 0; mi < 8; mi++) {
    int mp = m0 + tym * 8 + mi;
    bxv[mi] = Wxs[tym * 8 + mi][72] + bup[(mp >> 2) * 2 + (mp & 1)];
  }
  #pragma unroll
  for (int cg = 0; cg < 2; cg++) {
    int mp0 = m0 + tym * 8 + cg * 4;
    int c = mp0 >> 2;
    #pragma unroll
    for (int j = 0; j < 8; j++) {
      int n = n0 + txn * 8 + j;
      int b = n >> 11, t = n & 2047;
      float4 sv = make_float4(acc[cg * 4 + 0][j] + bxv[cg * 4 + 0],
                              acc[cg * 4 + 1][j] + bxv[cg * 4 + 1],
                              acc[cg * 4 + 2][j] + bxv[cg * 4 + 2],
                              acc[cg * 4 + 3][j] + bxv[cg * 4 + 3]);
      *(float4*)&xout[((size_t)((b << 9) + c)) * 8192 + 4 * t] = sv;
    }
  }
}

// ---------------- RVQ core (proven, unchanged) ----------------
__global__ __launch_bounds__(256) void rvq_kernel(const float* __restrict__ codebooks,
                                                  const float* __restrict__ e0t,
                                                  const float* __restrict__ cbsW,
                                                  const float* __restrict__ ptW,
                                                  const float* __restrict__ beffW,
                                                  float* __restrict__ Qout,
                                                  float* __restrict__ codesOut,
                                                  float* __restrict__ lossPart) {
  __shared__ float cbv[8][1024];
  __shared__ float cbs2[2][1024];
  __shared__ float Pt[36 * 65];
  __shared__ float est[16][72];
  __shared__ float lred[4];
  int tid = threadIdx.x, wid = tid >> 6, lane = tid & 63;
  int nb0 = blockIdx.x * 16;
  for (int idx = tid; idx < 2340; idx += 256) Pt[idx] = ptW[idx];
  for (int idx = tid; idx < 16 * 72; idx += 256)
    est[idx / 72][idx % 72] = e0t[(size_t)nb0 * 72 + idx] + beffW[idx % 72];
  float lossLocal = 0.f;

  for (int i = 0; i < NQ; i++) {
    __syncthreads();
    const float* cbg = codebooks + (size_t)i * CBS * CBD;
    for (int lin = tid; lin < 2048; lin += 256) {
      int j = lin >> 1, half = (lin & 1) << 2;
      float4 v = *(const float4*)(cbg + (size_t)j * 8 + half);
      cbv[half + 0][j] = v.x; cbv[half + 1][j] = v.y;
      cbv[half + 2][j] = v.z; cbv[half + 3][j] = v.w;
    }
    for (int lin = tid; lin < 1024; lin += 256) {
      cbs2[0][lin] = cbsW[((size_t)i * 2 + 0) * 1024 + lin];
      cbs2[1][lin] = cbsW[((size_t)i * 2 + 1) * 1024 + lin];
    }
    __syncthreads();

    float ze[4][8], en[4][8];
    #pragma unroll
    for (int w = 0; w < 4; w++) {
      int tokl = wid * 4 + w;
      float ss = 0.f;
      #pragma unroll
      for (int d = 0; d < 8; d++) { float v = est[tokl][i * 8 + d]; ze[w][d] = v; ss += v * v; }
      float inv = 1.0f / fmaxf(sqrtf(ss), EPSN);
      #pragma unroll
      for (int d = 0; d < 8; d++) en[w][d] = ze[w][d] * inv;
    }
    float best[4]; int bidx[4];
    #pragma unroll
    for (int w = 0; w < 4; w++) { best[w] = -INFINITY; bidx[w] = 0; }
    #pragma unroll 4
    for (int r = 0; r < 16; r++) {
      int j = lane + (r << 6);
      float c0 = cbv[0][j], c1 = cbv[1][j], c2 = cbv[2][j], c3 = cbv[3][j];
      float c4 = cbv[4][j], c5 = cbv[5][j], c6 = cbv[6][j], c7 = cbv[7][j];
      float ti = cbs2[0][j], ns = cbs2[1][j];
      #pragma unroll
      for (int w = 0; w < 4; w++) {
        float dt = en[w][0] * c0;
        dt = fmaf(en[w][1], c1, dt); dt = fmaf(en[w][2], c2, dt);
        dt = fmaf(en[w][3], c3, dt); dt = fmaf(en[w][4], c4, dt);
        dt = fmaf(en[w][5], c5, dt); dt = fmaf(en[w][6], c6, dt);
        dt = fmaf(en[w][7], c7, dt);
        float s = fmaf(dt, ti, -ns);
        if (s > best[w]) { best[w] = s; bidx[w] = j; }
      }
    }
    #pragma unroll
    for (int w = 0; w < 4; w++) {
      #pragma unroll
      for (int off = 32; off; off >>= 1) {
        float so = __shfl_xor(best[w], off);
        int jo = __shfl_xor(bidx[w], off);
        if (so > best[w] || (so == best[w] && jo < bidx[w])) { best[w] = so; bidx[w] = jo; }
      }
    }
    int d = lane & 7;
    #pragma unroll
    for (int w = 0; w < 4; w++) {
      int jstar = bidx[w];
      int tokl = wid * 4 + w;
      int n = nb0 + tokl;
      float qd = cbv[d][jstar];
      float diff = ze[w][d] - qd;
      float sq = diff * diff;
      sq += __shfl_xor(sq, 1); sq += __shfl_xor(sq, 2); sq += __shfl_xor(sq, 4);
      if (lane == 0) lossLocal += sq;
      if (lane < 8) Qout[(size_t)(i * 8 + lane) * NTOK + n] = qd;
      if (lane == 0) codesOut[(size_t)((n >> 11) * NQ + i) * TQ + (n & (TQ - 1))] = (float)jstar;
      if (i < NQ - 1) {
        int f = lane >> 3, d2 = lane & 7;
        int ip = i + 1 + f;
        if (ip < NQ) {
          int tri = (ip * (ip - 1)) / 2 + i;
          const float* prow = &Pt[tri * 65 + d2 * 8];
          float s = 0.f;
          #pragma unroll
          for (int dp = 0; dp < 8; dp++) s = fmaf(prow[dp], cbv[dp][jstar], s);
          est[tokl][ip * 8 + d2] -= s;
        }
      }
    }
  }
  if (lane == 0) lred[wid] = lossLocal;
  __syncthreads();
  if (tid == 0) {
    float s = ((lred[0] + lred[1]) + lred[2]) + lred[3];
    lossPart[blockIdx.x] = s;
  }
}

__global__ void loss_fin(const float* __restrict__ lossPart, float* __restrict__ out) {
  __shared__ float s[256];
  int tid = threadIdx.x;
  float v = 0.f;
  for (int r = 0; r < 4; r++) v += lossPart[tid + r * 256];
  s[tid] = v;
  __syncthreads();
  for (int w = 128; w; w >>= 1) {
    if (tid < w) s[tid] += s[tid + w];
    __syncthreads();
  }
  if (tid == 0) {
    float total = s[0] / 131072.0f;
    out[0] = total;
    out[1] = total;
  }
}

// ---------------- launch ----------------
extern "C" void kernel_launch(void* const* d_in, const int* in_sizes, int n_in,
                              void* d_out, int out_size, void* d_ws, size_t ws_size,
                              hipStream_t stream) {
  const float* z      = (const float*)d_in[0];
  const float* down_w = (const float*)d_in[1];
  const float* down_b = (const float*)d_in[2];
  const float* up_w   = (const float*)d_in[3];
  const float* up_b   = (const float*)d_in[4];
  const float* in_v   = (const float*)d_in[5];
  const float* in_g   = (const float*)d_in[6];
  const float* in_b   = (const float*)d_in[7];
  const float* out_v  = (const float*)d_in[8];
  const float* out_g  = (const float*)d_in[9];
  const float* out_b  = (const float*)d_in[10];
  const float* codebooks = (const float*)d_in[11];
  float* ws = (float*)d_ws;
  float* xout = (float*)d_out;
  float* codesOut = xout + (size_t)8 * 512 * 8192;
  float* lossOut = codesOut + (size_t)8 * NQ * TQ;

  hipLaunchKernelGGL(prep_small1, dim3(458), dim3(256), 0, stream,
                     in_v, in_g, out_v, out_g, out_b, codebooks,
                     down_w, down_b, up_w, up_b, ws);
  hipLaunchKernelGGL(prep2, dim3(594), dim3(256), 0, stream, in_b, out_b, ws);
  hipLaunchKernelGGL((smallmm<0>), dim3(8, 8, 4), dim3(256), 0, stream, down_w, ws + OFF_WD);
  hipLaunchKernelGGL((smallmm<1>), dim3(8, 8, 4), dim3(256), 0, stream, up_w, ws + OFF_WEFF);
  hipLaunchKernelGGL(prep_wdsplit, dim3(4096), dim3(256), 0, stream,
                     ws + OFF_WD, (u16*)(ws + OFF_WDP));
  hipLaunchKernelGGL(prep_wx, dim3(128), dim3(256), 0, stream,
                     ws + OFF_WEFF, ws + OFF_WOUTS, ws + OFF_WX);
  // fused down: x2 = W_d(3-split) @ zg + b_d  (128x128, 8 waves, bit-identical)
  hipLaunchKernelGGL(gemm_down, dim3(128, 4), dim3(512), 0, stream,
                     (const u16*)(ws + OFF_WDP), z, ws + OFF_BD, ws + OFF_X2);
  // e0t = WinN @ x2 (BN=64, full-chip)
  hipLaunchKernelGGL(gemm_e0f, dim3(256), dim3(256), 0, stream,
                     ws + OFF_WINN, ws + OFF_X2, ws + OFF_E0T);
  // RVQ
  hipLaunchKernelGGL(rvq_kernel, dim3(1024), dim3(256), 0, stream,
                     codebooks, ws + OFF_E0T, ws + OFF_CBS, ws + OFF_PT, ws + OFF_BEFF,
                     ws + OFF_Q, codesOut, ws + OFF_LOSS);
  // x = Wx @ Q + bx
  hipLaunchKernelGGL(xfin, dim3(128, 16), dim3(256), 0, stream,
                     ws + OFF_WX, ws + OFF_Q, ws + OFF_BUP, xout);
  hipLaunchKernelGGL(loss_fin, dim3(1), dim3(256), 0, stream, ws + OFF_LOSS, lossOut);
}

// Round 16
// 813.551 us; speedup vs baseline: 1.1504x; 1.1504x over previous
//
#include <hip/hip_runtime.h>
#include <math.h>

// FireflyVQ R16: R12-exact gemm_down geometry (128x128, 4 waves, 256 thr --
// the measured best: 277us) + A-fragment register double-buffer prefetch
// (pure scheduling, bit-exact). e0f full-chip (R14). Rest R12/R14 verbatim.

using u16 = unsigned short;
typedef __attribute__((ext_vector_type(8))) short bf16x8;
typedef __attribute__((ext_vector_type(8))) u16 su16x8;
typedef __attribute__((ext_vector_type(4))) float f32x4;

constexpr int NQ = 9, CBS = 1024, CBD = 8;
constexpr int TQ = 2048;
constexpr int NTOK = 16384;
constexpr int APS = 1048576;   // u16 per W_d split plane (512*2048)
#define EPSN 1e-12f

// ---- ws layout (float offsets), ~58.7 MB (R12's)
constexpr size_t OFF_X2    = 0;                  // [8][512][2048] fp32
constexpr size_t OFF_E0T   = 8388608;            // [16384][72]
constexpr size_t OFF_Q     = 9568256;            // [72][16384]
constexpr size_t OFF_WD    = 10747904;           // W_d [512][2048] fp32
constexpr size_t OFF_WDP   = 11796480;           // 3 u16 planes of W_d
constexpr size_t OFF_WEFF  = 13369344;           // W_eff [2048][512] fp32
constexpr size_t OFF_WX    = 14417920;           // Wx [2048][80]
constexpr size_t OFF_WINN  = 14581760;           // [72][512]
constexpr size_t OFF_WOUTS = 14618624;           // WoutS2 [512][80]
constexpr size_t OFF_CBS   = 14659584;           // [9][2][1024]
constexpr size_t OFF_PT    = 14678016;           // 2340
constexpr size_t OFF_BEFF  = 14680356;           // 72
constexpr size_t OFF_BSUM  = 14680428;           // 512
constexpr size_t OFF_BD    = 14680940;           // 512
constexpr size_t OFF_BUP   = 14681452;           // [512][2]
constexpr size_t OFF_LOSS  = 14682476;           // 1024

// ---------------- prep_small1 (R12 verbatim) ----------------
__global__ void prep_small1(const float* __restrict__ in_v, const float* __restrict__ in_g,
                            const float* __restrict__ out_v, const float* __restrict__ out_g,
                            const float* __restrict__ out_b, const float* __restrict__ codebooks,
                            const float* __restrict__ down_w, const float* __restrict__ down_b,
                            const float* __restrict__ up_w, const float* __restrict__ up_b,
                            float* __restrict__ ws) {
  int bid = blockIdx.x, tid = threadIdx.x;
  int wid4 = tid >> 6, lane = tid & 63;
  if (bid < 18) {  // WinN rows
    int wid = bid * 4 + wid4;
    if (wid < 72) {
      const float* v = in_v + (size_t)wid * 512;
      float ss = 0.f;
      for (int c = lane; c < 512; c += 64) ss += v[c] * v[c];
      #pragma unroll
      for (int o = 32; o; o >>= 1) ss += __shfl_xor(ss, o);
      float sc = in_g[wid] / sqrtf(ss);
      float* dst = ws + OFF_WINN + (size_t)wid * 512;
      for (int c = lane; c < 512; c += 64) dst[c] = v[c] * sc;
    }
  } else if (bid < 36) {  // WoutS2 [c][80], cols 0..71
    int r = (bid - 18) * 256 + tid;
    if (r < 4608) {
      int i = r >> 9, c = r & 511;
      const float* v = out_v + (size_t)r * 8;
      float ss = 0.f;
      #pragma unroll
      for (int d = 0; d < 8; d++) ss += v[d] * v[d];
      float sc = out_g[r] / sqrtf(ss);
      float* dst = ws + OFF_WOUTS + (size_t)c * 80 + i * 8;
      #pragma unroll
      for (int d = 0; d < 8; d++) dst[d] = v[d] * sc;
    }
  } else if (bid < 72) {  // codebook scalars
    int r = (bid - 36) * 256 + tid;
    if (r < 9216) {
      int i = r >> 10, j = r & 1023;
      const float* v = codebooks + (size_t)r * 8;
      float ss = 0.f;
      #pragma unroll
      for (int d = 0; d < 8; d++) ss += v[d] * v[d];
      float nm = fmaxf(sqrtf(ss), EPSN);
      float nsq = 0.f;
      #pragma unroll
      for (int d = 0; d < 8; d++) { float cn = v[d] / nm; nsq += cn * cn; }
      ws[OFF_CBS + ((size_t)i * 2 + 0) * 1024 + j] = 2.0f / nm;
      ws[OFF_CBS + ((size_t)i * 2 + 1) * 1024 + j] = nsq;
    }
  } else if (bid < 74) {  // bsum + WoutS2 col 72..79
    int c = (bid - 72) * 256 + tid;
    if (c < 512) {
      float s = 0.f;
      #pragma unroll
      for (int j = 0; j < 9; j++) s += out_b[j * 512 + c];
      ws[OFF_BSUM + c] = s;
      ws[OFF_WOUTS + (size_t)c * 80 + 72] = s;
      #pragma unroll
      for (int d = 73; d < 80; d++) ws[OFF_WOUTS + (size_t)c * 80 + d] = 0.f;
    }
  } else if (bid < 202) {  // b_d[o]
    int o = (bid - 74) * 4 + wid4;
    float s = 0.f;
    for (int m = lane; m < 512; m += 64) {
      float w0 = down_w[524288 + (size_t)o * 1024 + m * 2];
      float w1 = down_w[524288 + (size_t)o * 1024 + m * 2 + 1];
      s += (w0 + w1) * down_b[m];
    }
    #pragma unroll
    for (int off = 32; off; off >>= 1) s += __shfl_xor(s, off);
    if (lane == 0) ws[OFF_BD + o] = s + down_b[512 + o];
  } else {  // bup[c][j2]
    int gw = (bid - 202) * 4 + wid4;
    int c = gw >> 1, j2 = gw & 1;
    float s = 0.f;
    for (int m = lane; m < 512; m += 64)
      s += up_w[524288 + (size_t)m * 1024 + c * 2 + j2] * up_b[m];
    #pragma unroll
    for (int off = 32; off; off >>= 1) s += __shfl_xor(s, off);
    if (lane == 0) ws[OFF_BUP + gw] = s + up_b[512 + c];
  }
}

// ---------------- prep2 (R12 verbatim) ----------------
__global__ void prep2(const float* __restrict__ in_b, const float* __restrict__ out_b,
                      float* __restrict__ ws) {
  int gw = blockIdx.x * 4 + (threadIdx.x >> 6), lane = threadIdx.x & 63;
  const float* WinN = ws + OFF_WINN;
  const float* WoutS = ws + OFF_WOUTS;
  if (gw < 2304) {
    int tri = gw >> 6, dd = gw & 63;
    int ip = 1;
    while (tri >= ip * (ip + 1) / 2) ip++;
    int i = tri - ip * (ip - 1) / 2;
    int d = dd >> 3, dp = dd & 7;
    const float* a = WinN + (size_t)(ip * 8 + d) * 512;
    float s = 0.f;
    for (int c = lane; c < 512; c += 64) s += a[c] * WoutS[(size_t)c * 80 + i * 8 + dp];
    #pragma unroll
    for (int o = 32; o; o >>= 1) s += __shfl_xor(s, o);
    if (lane == 0) ws[OFF_PT + (size_t)tri * 65 + dd] = s;
  } else if (gw < 2376) {
    int r = gw - 2304;
    int i = r >> 3;
    const float* a = WinN + (size_t)r * 512;
    float s = 0.f;
    for (int c = lane; c < 512; c += 64) {
      float ob = 0.f;
      for (int j = 0; j < i; j++) ob += out_b[j * 512 + c];
      s += a[c] * ob;
    }
    #pragma unroll
    for (int o = 32; o; o >>= 1) s += __shfl_xor(s, o);
    if (lane == 0) ws[OFF_BEFF + r] = in_b[r] - s;
  }
}

// ---------------- smallmm (R12 verbatim) ----------------
template <int WHICH>
__global__ __launch_bounds__(256) void smallmm(const float* __restrict__ src,
                                               float* __restrict__ outp) {
  __shared__ float As[32][68];
  __shared__ float Bs[32][68];
  const int tid = threadIdx.x;
  const int tx = tid & 15, ty = tid >> 4;
  const int b0 = blockIdx.x * 64, a0 = blockIdx.y * 64, j = blockIdx.z;
  const int jh = j >> 1, jl = j & 1;
  float acc[4][4];
  #pragma unroll
  for (int i = 0; i < 4; i++)
    #pragma unroll
    for (int k = 0; k < 4; k++) acc[i][k] = 0.f;

  for (int k0 = 0; k0 < 512; k0 += 32) {
    #pragma unroll
    for (int rep = 0; rep < 8; rep++) {
      int f = tid + rep * 256;
      int aa = f >> 5, mm = f & 31;
      size_t ai;
      if constexpr (WHICH == 0) ai = 524288 + (size_t)(a0 + aa) * 1024 + (k0 + mm) * 2 + jh;
      else                      ai = 524288 + (size_t)(k0 + mm) * 1024 + (a0 + aa) * 2 + jl;
      As[mm][aa] = src[ai];
      int mm2 = f >> 6, bb = f & 63;
      size_t bi;
      if constexpr (WHICH == 0) bi = (size_t)(k0 + mm2) * 1024 + (b0 + bb) * 2 + jl;
      else                      bi = (size_t)(b0 + bb) * 1024 + (k0 + mm2) * 2 + jh;
      Bs[mm2][bb] = src[bi];
    }
    __syncthreads();
    #pragma unroll
    for (int kk = 0; kk < 32; kk++) {
      float av[4], bv[4];
      #pragma unroll
      for (int i = 0; i < 4; i++) av[i] = As[kk][ty * 4 + i];
      #pragma unroll
      for (int i = 0; i < 4; i++) bv[i] = Bs[kk][tx * 4 + i];
      #pragma unroll
      for (int i = 0; i < 4; i++)
        #pragma unroll
        for (int k = 0; k < 4; k++) acc[i][k] = fmaf(av[i], bv[k], acc[i][k]);
    }
    __syncthreads();
  }
  #pragma unroll
  for (int i = 0; i < 4; i++) {
    int a = a0 + ty * 4 + i;
    #pragma unroll
    for (int k = 0; k < 4; k++) {
      int b = b0 + tx * 4 + k;
      if constexpr (WHICH == 0) outp[(size_t)a * 2048 + b * 4 + j] = acc[i][k];
      else                      outp[((size_t)a * 4 + j) * 512 + b] = acc[i][k];
    }
  }
}

// ---------------- prep_wdsplit (R12 verbatim) ----------------
__global__ void prep_wdsplit(const float* __restrict__ wd, u16* __restrict__ wdp) {
  int idx = blockIdx.x * 256 + threadIdx.x;
  float v = wd[idx];
  unsigned u = __float_as_uint(v);
  wdp[idx] = (u16)(u >> 16);
  float r = v - __uint_as_float(u & 0xFFFF0000u);
  unsigned ur = __float_as_uint(r);
  wdp[APS + idx] = (u16)(ur >> 16);
  float r2 = r - __uint_as_float(ur & 0xFFFF0000u);
  wdp[2 * APS + idx] = (u16)(__float_as_uint(r2) >> 16);
}

// ---------------- prep_wx (R12 verbatim) ----------------
__global__ __launch_bounds__(256) void prep_wx(const float* __restrict__ weff,
                                               const float* __restrict__ wouts,
                                               float* __restrict__ wx) {
  __shared__ float Wes[16][512];
  __shared__ float WSs[64][80];
  const int tid = threadIdx.x;
  const int m0 = blockIdx.x * 16;
  #pragma unroll
  for (int rep = 0; rep < 32; rep++) {
    int f = tid + rep * 256;
    Wes[f >> 9][f & 511] = weff[(size_t)(m0 + (f >> 9)) * 512 + (f & 511)];
  }
  const int rowq = tid >> 4, rq = tid & 15;
  float accs[5] = {0.f, 0.f, 0.f, 0.f, 0.f};
  for (int k0 = 0; k0 < 512; k0 += 64) {
    __syncthreads();
    #pragma unroll
    for (int rep = 0; rep < 20; rep++) {
      int f = tid + rep * 256;
      int kk = f / 80, col = f % 80;
      WSs[kk][col] = wouts[(size_t)(k0 + kk) * 80 + col];
    }
    __syncthreads();
    #pragma unroll 4
    for (int kk = 0; kk < 64; kk++) {
      float we = Wes[rowq][k0 + kk];
      #pragma unroll
      for (int s = 0; s < 5; s++) accs[s] = fmaf(we, WSs[kk][rq + 16 * s], accs[s]);
    }
  }
  #pragma unroll
  for (int s = 0; s < 5; s++) {
    int r = rq + 16 * s;
    if (r < 73) wx[(size_t)(m0 + rowq) * 80 + r] = accs[s];
  }
  if (tid < 112) {
    int row = tid / 7, col = 73 + tid % 7;
    wx[(size_t)(m0 + row) * 80 + col] = 0.f;
  }
}

// ---------------- gemm_down: R12 geometry + A-register prefetch ----------------
// 128x128 tile, 4 waves (2x2, each 64x64), 256 thr, grid (128,4)=512 blocks.
// Splits / K order / 6-MFMA order / epilogue identical to R12 -> bit-exact.
// NEW (scheduling only): A fragments double-buffered in registers one K-step
// ahead (issued right after barrier); B frags loaded per-fn to cap VGPR.
__global__ __launch_bounds__(256) void gemm_down(const u16* __restrict__ Ap,
                                                 const float* __restrict__ z,
                                                 const float* __restrict__ bias,
                                                 float* __restrict__ Out) {
  constexpr int NS = 3, K = 2048;
  __shared__ u16 Bp[2][NS][128][32];
  const int tid = threadIdx.x;
  const int w = tid >> 6, l = tid & 63;
  const int g = l >> 4, li = l & 15;
  const int wr = w >> 1, wc = w & 1;
  const int n0 = blockIdx.x * 128, m0 = blockIdx.y * 128;
  const int nn = tid & 127, kw = tid >> 7;
  const int bb = n0 >> 11;
  const int tb = (n0 & 2047) + nn;

  f32x4 acc[4][4];
  #pragma unroll
  for (int a = 0; a < 4; a++)
    #pragma unroll
    for (int b = 0; b < 4; b++) acc[a][b] = (f32x4){0.f, 0.f, 0.f, 0.f};

  float pvA[16], pvB[16];
  bf16x8 afrA[4][NS], afrB[4][NS];
  const u16* arow = Ap + (size_t)(m0 + wr * 64 + li) * K + g * 8;

#define LOADB(PV, K0)                                                           \
  {                                                                             \
    int c0_ = ((K0) >> 2) + kw * 4;                                             \
    _Pragma("unroll")                                                           \
    for (int cc_ = 0; cc_ < 4; ++cc_)                                           \
      *(float4*)&PV[4 * cc_] =                                                  \
          *(const float4*)(z + ((size_t)(bb * 512 + c0_ + cc_) << 13) + 4 * tb);\
  }

#define LOADA(DST, K0)                                                          \
  {                                                                             \
    _Pragma("unroll")                                                           \
    for (int fm_ = 0; fm_ < 4; ++fm_)                                           \
      _Pragma("unroll")                                                         \
      for (int p_ = 0; p_ < NS; ++p_)                                           \
        DST[fm_][p_] = *(const bf16x8*)(arow + (size_t)p_ * APS +               \
                                        (size_t)fm_ * 16 * K + (K0));           \
  }

  const int sw = (nn >> 1) & 3;
  const int c0 = ((2 * kw) ^ sw) << 3, c1 = ((2 * kw + 1) ^ sw) << 3;

#define STAGE(BUF, PV)                                                          \
  {                                                                             \
    su16x8 pa_[NS], pb_[NS];                                                    \
    _Pragma("unroll")                                                           \
    for (int j_ = 0; j_ < 8; ++j_) {                                            \
      {                                                                         \
        float v_ = PV[j_];                                                      \
        unsigned u_ = __float_as_uint(v_);                                      \
        pa_[0][j_] = (u16)(u_ >> 16);                                           \
        float r_ = v_ - __uint_as_float(u_ & 0xFFFF0000u);                      \
        unsigned ur_ = __float_as_uint(r_);                                     \
        pa_[1][j_] = (u16)(ur_ >> 16);                                          \
        float r2_ = r_ - __uint_as_float(ur_ & 0xFFFF0000u);                    \
        pa_[2][j_] = (u16)(__float_as_uint(r2_) >> 16);                         \
      }                                                                         \
      {                                                                         \
        float v_ = PV[8 + j_];                                                  \
        unsigned u_ = __float_as_uint(v_);                                      \
        pb_[0][j_] = (u16)(u_ >> 16);                                           \
        float r_ = v_ - __uint_as_float(u_ & 0xFFFF0000u);                      \
        unsigned ur_ = __float_as_uint(r_);                                     \
        pb_[1][j_] = (u16)(ur_ >> 16);                                          \
        float r2_ = r_ - __uint_as_float(ur_ & 0xFFFF0000u);                    \
        pb_[2][j_] = (u16)(__float_as_uint(r2_) >> 16);                         \
      }                                                                         \
    }                                                                           \
    _Pragma("unroll")                                                           \
    for (int p_ = 0; p_ < NS; ++p_) {                                           \
      *(su16x8*)&Bp[BUF][p_][nn][c0] = pa_[p_];                                 \
      *(su16x8*)&Bp[BUF][p_][nn][c1] = pb_[p_];                                 \
    }                                                                           \
  }

#define COMPUTE(BUF, AFR)                                                       \
  {                                                                             \
    _Pragma("unroll")                                                           \
    for (int fn_ = 0; fn_ < 4; ++fn_) {                                         \
      int row_ = wc * 64 + fn_ * 16 + li;                                       \
      int cs_ = ((g ^ ((row_ >> 1) & 3)) << 3);                                 \
      bf16x8 bfr_[NS];                                                          \
      _Pragma("unroll")                                                         \
      for (int q_ = 0; q_ < NS; ++q_)                                           \
        bfr_[q_] = *(const bf16x8*)&Bp[BUF][q_][row_][cs_];                     \
      _Pragma("unroll")                                                         \
      for (int fm_ = 0; fm_ < 4; ++fm_) {                                       \
        f32x4 a_ = acc[fm_][fn_];                                               \
        a_ = __builtin_amdgcn_mfma_f32_16x16x32_bf16(AFR[fm_][2], bfr_[0], a_, 0, 0, 0); \
        a_ = __builtin_amdgcn_mfma_f32_16x16x32_bf16(AFR[fm_][1], bfr_[1], a_, 0, 0, 0); \
        a_ = __builtin_amdgcn_mfma_f32_16x16x32_bf16(AFR[fm_][0], bfr_[2], a_, 0, 0, 0); \
        a_ = __builtin_amdgcn_mfma_f32_16x16x32_bf16(AFR[fm_][1], bfr_[0], a_, 0, 0, 0); \
        a_ = __builtin_amdgcn_mfma_f32_16x16x32_bf16(AFR[fm_][0], bfr_[1], a_, 0, 0, 0); \
        a_ = __builtin_amdgcn_mfma_f32_16x16x32_bf16(AFR[fm_][0], bfr_[0], a_, 0, 0, 0); \
        acc[fm_][fn_] = a_;                                                     \
      }                                                                         \
    }                                                                           \
  }

  LOADB(pvA, 0)
  LOADB(pvB, 32)
  STAGE(0, pvA)
  LOADB(pvA, 64)
  LOADA(afrA, 0)
  __syncthreads();

  for (int k0 = 0; k0 < K; k0 += 64) {
    STAGE(1, pvB)
    if (k0 + 96 < K) { LOADB(pvB, k0 + 96) }
    LOADA(afrB, k0 + 32)
    COMPUTE(0, afrA)
    __syncthreads();
    if (k0 + 64 < K) { STAGE(0, pvA) }
    if (k0 + 128 < K) { LOADB(pvA, k0 + 128) }
    if (k0 + 64 < K) { LOADA(afrA, k0 + 64) }
    COMPUTE(1, afrB)
    __syncthreads();
  }
#undef LOADB
#undef LOADA
#undef STAGE
#undef COMPUTE

  const int mb = m0 + wr * 64 + g * 4;
  const int nb = n0 + wc * 64 + li;
  #pragma unroll
  for (int fn = 0; fn < 4; ++fn) {
    int n = nb + fn * 16;
    int b = n >> 11, t = n & 2047;
    #pragma unroll
    for (int fm = 0; fm < 4; ++fm)
      #pragma unroll
      for (int r = 0; r < 4; ++r) {
        int o = mb + fm * 16 + r;
        Out[((size_t)((b << 9) + o)) * 2048 + t] = acc[fm][fn][r] + bias[o];
      }
  }
}

// ---------------- gemm_e0f (R14 verbatim): e0t = WinN @ x2, BN=64 ----------------
__global__ __launch_bounds__(256) void gemm_e0f(const float* __restrict__ A,
                                                const float* __restrict__ Bsrc,
                                                float* __restrict__ e0t) {
  constexpr int M = 72, K = 512, Tt = 2048;
  __shared__ float As[16][132];
  __shared__ float Bs[16][68];
  int tid = threadIdx.x;
  int tx = tid & 7, ty = tid >> 3;
  int n0 = blockIdx.x * 64;
  int b = n0 / Tt, t0 = n0 % Tt;
  float acc[4][8];
  #pragma unroll
  for (int i = 0; i < 4; i++)
    #pragma unroll
    for (int j = 0; j < 8; j++) acc[i][j] = 0.f;

  for (int k0 = 0; k0 < K; k0 += 16) {
    #pragma unroll
    for (int rep = 0; rep < 2; rep++) {
      int f = tid + rep * 256;
      int row = f >> 2, c4 = (f & 3) << 2;
      int m = row, k = k0 + c4;
      float4 v = make_float4(0.f, 0.f, 0.f, 0.f);
      if (m < M) v = *(const float4*)(A + (size_t)m * K + k);
      As[c4 + 0][row] = v.x; As[c4 + 1][row] = v.y;
      As[c4 + 2][row] = v.z; As[c4 + 3][row] = v.w;
    }
    {
      int kk = tid >> 4, n4 = (tid & 15) << 2;
      float4 v = *(const float4*)(Bsrc + ((size_t)(b * K + k0 + kk)) * Tt + t0 + n4);
      *(float4*)&Bs[kk][n4] = v;
    }
    __syncthreads();
    #pragma unroll
    for (int kk = 0; kk < 16; kk++) {
      float a[4], bb[8];
      #pragma unroll
      for (int i = 0; i < 4; i++) a[i] = As[kk][ty * 4 + i];
      *(float4*)&bb[0] = *(float4*)&Bs[kk][tx * 8];
      *(float4*)&bb[4] = *(float4*)&Bs[kk][tx * 8 + 4];
      #pragma unroll
      for (int i = 0; i < 4; i++)
        #pragma unroll
        for (int j = 0; j < 8; j++) acc[i][j] = fmaf(a[i], bb[j], acc[i][j]);
    }
    __syncthreads();
  }
  #pragma unroll
  for (int j = 0; j < 8; j++) {
    int n = n0 + tx * 8 + j;
    #pragma unroll
    for (int i = 0; i < 4; i++) {
      int m = ty * 4 + i;
      if (m < M) e0t[(size_t)n * M + m] = acc[i][j];
    }
  }
}

// ---------------- xfin (R12 verbatim) ----------------
__global__ __launch_bounds__(256) void xfin(const float* __restrict__ wx,
                                            const float* __restrict__ Q,
                                            const float* __restrict__ bup,
                                            float* __restrict__ xout) {
  __shared__ float Wxs[128][80];
  __shared__ float Qs[128][80];
  const int tid = threadIdx.x;
  const int n0 = blockIdx.x * 128, m0 = blockIdx.y * 128;
  #pragma unroll
  for (int rep = 0; rep < 10; rep++) {
    int f = tid + rep * 256;
    *(float4*)&Wxs[0][f * 4] = *(const float4*)(wx + (size_t)m0 * 80 + f * 4);
  }
  {
    int nn = tid & 127, r0 = tid >> 7;
    for (int r = r0; r < 72; r += 2)
      Qs[nn][r] = Q[(size_t)r * 16384 + n0 + nn];
  }
  __syncthreads();

  const int txn = tid & 15, tym = tid >> 4;
  float acc[8][8];
  #pragma unroll
  for (int i = 0; i < 8; i++)
    #pragma unroll
    for (int j = 0; j < 8; j++) acc[i][j] = 0.f;

  #pragma unroll 2
  for (int r4 = 0; r4 < 18; r4++) {
    float4 wv[8], qv[8];
    #pragma unroll
    for (int i = 0; i < 8; i++) wv[i] = *(const float4*)&Wxs[tym * 8 + i][r4 * 4];
    #pragma unroll
    for (int j = 0; j < 8; j++) qv[j] = *(const float4*)&Qs[txn * 8 + j][r4 * 4];
    #pragma unroll
    for (int i = 0; i < 8; i++)
      #pragma unroll
      for (int j = 0; j < 8; j++) {
        acc[i][j] = fmaf(wv[i].x, qv[j].x, acc[i][j]);
        acc[i][j] = fmaf(wv[i].y, qv[j].y, acc[i][j]);
        acc[i][j] = fmaf(wv[i].z, qv[j].z, acc[i][j]);
        acc[i][j] = fmaf(wv[i].w, qv[j].w, acc[i][j]);
      }
  }

  float bxv[8];
  #pragma unroll
  for (int mi = 0; mi < 8; mi++) {
    int mp = m0 + tym * 8 + mi;
    bxv[mi] = Wxs[tym * 8 + mi][72] + bup[(mp >> 2) * 2 + (mp & 1)];
  }
  #pragma unroll
  for (int cg = 0; cg < 2; cg++) {
    int mp0 = m0 + tym * 8 + cg * 4;
    int c = mp0 >> 2;
    #pragma unroll
    for (int j = 0; j < 8; j++) {
      int n = n0 + txn * 8 + j;
      int b = n >> 11, t = n & 2047;
      float4 sv = make_float4(acc[cg * 4 + 0][j] + bxv[cg * 4 + 0],
                              acc[cg * 4 + 1][j] + bxv[cg * 4 + 1],
                              acc[cg * 4 + 2][j] + bxv[cg * 4 + 2],
                              acc[cg * 4 + 3][j] + bxv[cg * 4 + 3]);
      *(float4*)&xout[((size_t)((b << 9) + c)) * 8192 + 4 * t] = sv;
    }
  }
}

// ---------------- RVQ core (proven, unchanged) ----------------
__global__ __launch_bounds__(256) void rvq_kernel(const float* __restrict__ codebooks,
                                                  const float* __restrict__ e0t,
                                                  const float* __restrict__ cbsW,
                                                  const float* __restrict__ ptW,
                                                  const float* __restrict__ beffW,
                                                  float* __restrict__ Qout,
                                                  float* __restrict__ codesOut,
                                                  float* __restrict__ lossPart) {
  __shared__ float cbv[8][1024];
  __shared__ float cbs2[2][1024];
  __shared__ float Pt[36 * 65];
  __shared__ float est[16][72];
  __shared__ float lred[4];
  int tid = threadIdx.x, wid = tid >> 6, lane = tid & 63;
  int nb0 = blockIdx.x * 16;
  for (int idx = tid; idx < 2340; idx += 256) Pt[idx] = ptW[idx];
  for (int idx = tid; idx < 16 * 72; idx += 256)
    est[idx / 72][idx % 72] = e0t[(size_t)nb0 * 72 + idx] + beffW[idx % 72];
  float lossLocal = 0.f;

  for (int i = 0; i < NQ; i++) {
    __syncthreads();
    const float* cbg = codebooks + (size_t)i * CBS * CBD;
    for (int lin = tid; lin < 2048; lin += 256) {
      int j = lin >> 1, half = (lin & 1) << 2;
      float4 v = *(const float4*)(cbg + (size_t)j * 8 + half);
      cbv[half + 0][j] = v.x; cbv[half + 1][j] = v.y;
      cbv[half + 2][j] = v.z; cbv[half + 3][j] = v.w;
    }
    for (int lin = tid; lin < 1024; lin += 256) {
      cbs2[0][lin] = cbsW[((size_t)i * 2 + 0) * 1024 + lin];
      cbs2[1][lin] = cbsW[((size_t)i * 2 + 1) * 1024 + lin];
    }
    __syncthreads();

    float ze[4][8], en[4][8];
    #pragma unroll
    for (int w = 0; w < 4; w++) {
      int tokl = wid * 4 + w;
      float ss = 0.f;
      #pragma unroll
      for (int d = 0; d < 8; d++) { float v = est[tokl][i * 8 + d]; ze[w][d] = v; ss += v * v; }
      float inv = 1.0f / fmaxf(sqrtf(ss), EPSN);
      #pragma unroll
      for (int d = 0; d < 8; d++) en[w][d] = ze[w][d] * inv;
    }
    float best[4]; int bidx[4];
    #pragma unroll
    for (int w = 0; w < 4; w++) { best[w] = -INFINITY; bidx[w] = 0; }
    #pragma unroll 4
    for (int r = 0; r < 16; r++) {
      int j = lane + (r << 6);
      float c0 = cbv[0][j], c1 = cbv[1][j], c2 = cbv[2][j], c3 = cbv[3][j];
      float c4 = cbv[4][j], c5 = cbv[5][j], c6 = cbv[6][j], c7 = cbv[7][j];
      float ti = cbs2[0][j], ns = cbs2[1][j];
      #pragma unroll
      for (int w = 0; w < 4; w++) {
        float dt = en[w][0] * c0;
        dt = fmaf(en[w][1], c1, dt); dt = fmaf(en[w][2], c2, dt);
        dt = fmaf(en[w][3], c3, dt); dt = fmaf(en[w][4], c4, dt);
        dt = fmaf(en[w][5], c5, dt); dt = fmaf(en[w][6], c6, dt);
        dt = fmaf(en[w][7], c7, dt);
        float s = fmaf(dt, ti, -ns);
        if (s > best[w]) { best[w] = s; bidx[w] = j; }
      }
    }
    #pragma unroll
    for (int w = 0; w < 4; w++) {
      #pragma unroll
      for (int off = 32; off; off >>= 1) {
        float so = __shfl_xor(best[w], off);
        int jo = __shfl_xor(bidx[w], off);
        if (so > best[w] || (so == best[w] && jo < bidx[w])) { best[w] = so; bidx[w] = jo; }
      }
    }
    int d = lane & 7;
    #pragma unroll
    for (int w = 0; w < 4; w++) {
      int jstar = bidx[w];
      int tokl = wid * 4 + w;
      int n = nb0 + tokl;
      float qd = cbv[d][jstar];
      float diff = ze[w][d] - qd;
      float sq = diff * diff;
      sq += __shfl_xor(sq, 1); sq += __shfl_xor(sq, 2); sq += __shfl_xor(sq, 4);
      if (lane == 0) lossLocal += sq;
      if (lane < 8) Qout[(size_t)(i * 8 + lane) * NTOK + n] = qd;
      if (lane == 0) codesOut[(size_t)((n >> 11) * NQ + i) * TQ + (n & (TQ - 1))] = (float)jstar;
      if (i < NQ - 1) {
        int f = lane >> 3, d2 = lane & 7;
        int ip = i + 1 + f;
        if (ip < NQ) {
          int tri = (ip * (ip - 1)) / 2 + i;
          const float* prow = &Pt[tri * 65 + d2 * 8];
          float s = 0.f;
          #pragma unroll
          for (int dp = 0; dp < 8; dp++) s = fmaf(prow[dp], cbv[dp][jstar], s);
          est[tokl][ip * 8 + d2] -= s;
        }
      }
    }
  }
  if (lane == 0) lred[wid] = lossLocal;
  __syncthreads();
  if (tid == 0) {
    float s = ((lred[0] + lred[1]) + lred[2]) + lred[3];
    lossPart[blockIdx.x] = s;
  }
}

__global__ void loss_fin(const float* __restrict__ lossPart, float* __restrict__ out) {
  __shared__ float s[256];
  int tid = threadIdx.x;
  float v = 0.f;
  for (int r = 0; r < 4; r++) v += lossPart[tid + r * 256];
  s[tid] = v;
  __syncthreads();
  for (int w = 128; w; w >>= 1) {
    if (tid < w) s[tid] += s[tid + w];
    __syncthreads();
  }
  if (tid == 0) {
    float total = s[0] / 131072.0f;
    out[0] = total;
    out[1] = total;
  }
}

// ---------------- launch ----------------
extern "C" void kernel_launch(void* const* d_in, const int* in_sizes, int n_in,
                              void* d_out, int out_size, void* d_ws, size_t ws_size,
                              hipStream_t stream) {
  const float* z      = (const float*)d_in[0];
  const float* down_w = (const float*)d_in[1];
  const float* down_b = (const float*)d_in[2];
  const float* up_w   = (const float*)d_in[3];
  const float* up_b   = (const float*)d_in[4];
  const float* in_v   = (const float*)d_in[5];
  const float* in_g   = (const float*)d_in[6];
  const float* in_b   = (const float*)d_in[7];
  const float* out_v  = (const float*)d_in[8];
  const float* out_g  = (const float*)d_in[9];
  const float* out_b  = (const float*)d_in[10];
  const float* codebooks = (const float*)d_in[11];
  float* ws = (float*)d_ws;
  float* xout = (float*)d_out;
  float* codesOut = xout + (size_t)8 * 512 * 8192;
  float* lossOut = codesOut + (size_t)8 * NQ * TQ;

  hipLaunchKernelGGL(prep_small1, dim3(458), dim3(256), 0, stream,
                     in_v, in_g, out_v, out_g, out_b, codebooks,
                     down_w, down_b, up_w, up_b, ws);
  hipLaunchKernelGGL(prep2, dim3(594), dim3(256), 0, stream, in_b, out_b, ws);
  hipLaunchKernelGGL((smallmm<0>), dim3(8, 8, 4), dim3(256), 0, stream, down_w, ws + OFF_WD);
  hipLaunchKernelGGL((smallmm<1>), dim3(8, 8, 4), dim3(256), 0, stream, up_w, ws + OFF_WEFF);
  hipLaunchKernelGGL(prep_wdsplit, dim3(4096), dim3(256), 0, stream,
                     ws + OFF_WD, (u16*)(ws + OFF_WDP));
  hipLaunchKernelGGL(prep_wx, dim3(128), dim3(256), 0, stream,
                     ws + OFF_WEFF, ws + OFF_WOUTS, ws + OFF_WX);
  // fused down: x2 = W_d(3-split) @ zg + b_d  (R12 geometry + A-prefetch)
  hipLaunchKernelGGL(gemm_down, dim3(128, 4), dim3(256), 0, stream,
                     (const u16*)(ws + OFF_WDP), z, ws + OFF_BD, ws + OFF_X2);
  // e0t = WinN @ x2 (BN=64, full-chip)
  hipLaunchKernelGGL(gemm_e0f, dim3(256), dim3(256), 0, stream,
                     ws + OFF_WINN, ws + OFF_X2, ws + OFF_E0T);
  // RVQ
  hipLaunchKernelGGL(rvq_kernel, dim3(1024), dim3(256), 0, stream,
                     codebooks, ws + OFF_E0T, ws + OFF_CBS, ws + OFF_PT, ws + OFF_BEFF,
                     ws + OFF_Q, codesOut, ws + OFF_LOSS);
  // x = Wx @ Q + bx
  hipLaunchKernelGGL(xfin, dim3(128, 16), dim3(256), 0, stream,
                     ws + OFF_WX, ws + OFF_Q, ws + OFF_BUP, xout);
  hipLaunchKernelGGL(loss_fin, dim3(1), dim3(256), 0, stream, ws + OFF_LOSS, lossOut);
}

// Round 17
// 780.380 us; speedup vs baseline: 1.1993x; 1.0425x over previous
//
#include <hip/hip_runtime.h>
#include <math.h>

// FireflyVQ R17: R12-exact gemm_down (277us best; R16 A-prefetch reverted).
// Rest-shaving, all bit-exact-safe: rvq Pt->global (3 blk/CU), Q n-major
// (contig rvq writes + coalesced xfin staging), bup recoalesced (x-only),
// launch fusion 11->9 kernels. e0f full-chip (R14).

using u16 = unsigned short;
typedef __attribute__((ext_vector_type(8))) short bf16x8;
typedef __attribute__((ext_vector_type(8))) u16 su16x8;
typedef __attribute__((ext_vector_type(4))) float f32x4;

constexpr int NQ = 9, CBS = 1024, CBD = 8;
constexpr int TQ = 2048;
constexpr int NTOK = 16384;
constexpr int APS = 1048576;   // u16 per W_d split plane (512*2048)
#define EPSN 1e-12f

// ---- ws layout (float offsets), ~56.5 MB
constexpr size_t OFF_X2    = 0;                  // [8][512][2048] fp32
constexpr size_t OFF_E0T   = 8388608;            // [16384][72]
constexpr size_t OFF_Q     = 9568256;            // [16384][80] n-major
constexpr size_t OFF_WD    = 10878976;           // W_d [512][2048] fp32
constexpr size_t OFF_WDP   = 11927552;           // 3 u16 planes of W_d
constexpr size_t OFF_WEFF  = 13500416;           // W_eff [2048][512] fp32
constexpr size_t OFF_WX    = 14548992;           // Wx [2048][80]
constexpr size_t OFF_WINN  = 14712832;           // [72][512]
constexpr size_t OFF_WOUTS = 14749696;           // WoutS2 [512][80]
constexpr size_t OFF_CBS   = 14790656;           // [9][2][1024]
constexpr size_t OFF_PT    = 14809088;           // 2340
constexpr size_t OFF_BEFF  = 14811428;           // 72
constexpr size_t OFF_BSUM  = 14811500;           // 512
constexpr size_t OFF_BD    = 14812012;           // 512
constexpr size_t OFF_BUP   = 14812524;           // [512][2]
constexpr size_t OFF_LOSS  = 14813548;           // 1024

// ---------------- prep_small1 (R12 sections; bup recoalesced) ----------------
__global__ void prep_small1(const float* __restrict__ in_v, const float* __restrict__ in_g,
                            const float* __restrict__ out_v, const float* __restrict__ out_g,
                            const float* __restrict__ out_b, const float* __restrict__ codebooks,
                            const float* __restrict__ down_w, const float* __restrict__ down_b,
                            const float* __restrict__ up_w, const float* __restrict__ up_b,
                            float* __restrict__ ws) {
  int bid = blockIdx.x, tid = threadIdx.x;
  int wid4 = tid >> 6, lane = tid & 63;
  if (bid < 18) {  // WinN rows (locked chain)
    int wid = bid * 4 + wid4;
    if (wid < 72) {
      const float* v = in_v + (size_t)wid * 512;
      float ss = 0.f;
      for (int c = lane; c < 512; c += 64) ss += v[c] * v[c];
      #pragma unroll
      for (int o = 32; o; o >>= 1) ss += __shfl_xor(ss, o);
      float sc = in_g[wid] / sqrtf(ss);
      float* dst = ws + OFF_WINN + (size_t)wid * 512;
      for (int c = lane; c < 512; c += 64) dst[c] = v[c] * sc;
    }
  } else if (bid < 36) {  // WoutS2 [c][80], cols 0..71 (locked)
    int r = (bid - 18) * 256 + tid;
    if (r < 4608) {
      int i = r >> 9, c = r & 511;
      const float* v = out_v + (size_t)r * 8;
      float ss = 0.f;
      #pragma unroll
      for (int d = 0; d < 8; d++) ss += v[d] * v[d];
      float sc = out_g[r] / sqrtf(ss);
      float* dst = ws + OFF_WOUTS + (size_t)c * 80 + i * 8;
      #pragma unroll
      for (int d = 0; d < 8; d++) dst[d] = v[d] * sc;
    }
  } else if (bid < 72) {  // codebook scalars (locked)
    int r = (bid - 36) * 256 + tid;
    if (r < 9216) {
      int i = r >> 10, j = r & 1023;
      const float* v = codebooks + (size_t)r * 8;
      float ss = 0.f;
      #pragma unroll
      for (int d = 0; d < 8; d++) ss += v[d] * v[d];
      float nm = fmaxf(sqrtf(ss), EPSN);
      float nsq = 0.f;
      #pragma unroll
      for (int d = 0; d < 8; d++) { float cn = v[d] / nm; nsq += cn * cn; }
      ws[OFF_CBS + ((size_t)i * 2 + 0) * 1024 + j] = 2.0f / nm;
      ws[OFF_CBS + ((size_t)i * 2 + 1) * 1024 + j] = nsq;
    }
  } else if (bid < 74) {  // bsum + WoutS2 col 72..79 (locked)
    int c = (bid - 72) * 256 + tid;
    if (c < 512) {
      float s = 0.f;
      #pragma unroll
      for (int j = 0; j < 9; j++) s += out_b[j * 512 + c];
      ws[OFF_BSUM + c] = s;
      ws[OFF_WOUTS + (size_t)c * 80 + 72] = s;
      #pragma unroll
      for (int d = 73; d < 80; d++) ws[OFF_WOUTS + (size_t)c * 80 + d] = 0.f;
    }
  } else if (bid < 202) {  // b_d[o] (locked chain: lane-strided + shfl)
    int o = (bid - 74) * 4 + wid4;
    float s = 0.f;
    for (int m = lane; m < 512; m += 64) {
      float w0 = down_w[524288 + (size_t)o * 1024 + m * 2];
      float w1 = down_w[524288 + (size_t)o * 1024 + m * 2 + 1];
      s += (w0 + w1) * down_b[m];
    }
    #pragma unroll
    for (int off = 32; off; off >>= 1) s += __shfl_xor(s, off);
    if (lane == 0) ws[OFF_BD + o] = s + down_b[512 + o];
  } else {  // bid 202..205: bup (x-only, free) -- thread per (c,j2), coalesced
    int gw = (bid - 202) * 256 + tid;   // [0,1024)
    int c = gw >> 1, j2 = gw & 1;
    float s = 0.f;
    for (int m = 0; m < 512; m++)
      s += up_w[524288 + (size_t)m * 1024 + c * 2 + j2] * up_b[m];
    ws[OFF_BUP + gw] = s + up_b[512 + c];
  }
}

// ---------------- prep2 (R12 verbatim; locked) ----------------
__global__ void prep2(const float* __restrict__ in_b, const float* __restrict__ out_b,
                      float* __restrict__ ws) {
  int gw = blockIdx.x * 4 + (threadIdx.x >> 6), lane = threadIdx.x & 63;
  const float* WinN = ws + OFF_WINN;
  const float* WoutS = ws + OFF_WOUTS;
  if (gw < 2304) {
    int tri = gw >> 6, dd = gw & 63;
    int ip = 1;
    while (tri >= ip * (ip + 1) / 2) ip++;
    int i = tri - ip * (ip - 1) / 2;
    int d = dd >> 3, dp = dd & 7;
    const float* a = WinN + (size_t)(ip * 8 + d) * 512;
    float s = 0.f;
    for (int c = lane; c < 512; c += 64) s += a[c] * WoutS[(size_t)c * 80 + i * 8 + dp];
    #pragma unroll
    for (int o = 32; o; o >>= 1) s += __shfl_xor(s, o);
    if (lane == 0) ws[OFF_PT + (size_t)tri * 65 + dd] = s;
  } else if (gw < 2376) {
    int r = gw - 2304;
    int i = r >> 3;
    const float* a = WinN + (size_t)r * 512;
    float s = 0.f;
    for (int c = lane; c < 512; c += 64) {
      float ob = 0.f;
      for (int j = 0; j < i; j++) ob += out_b[j * 512 + c];
      s += a[c] * ob;
    }
    #pragma unroll
    for (int o = 32; o; o >>= 1) s += __shfl_xor(s, o);
    if (lane == 0) ws[OFF_BEFF + r] = in_b[r] - s;
  }
}

// ---------------- smallmm merged: grid (8,8,8); z<4 -> W_d j=z, else W_eff ----------------
__global__ __launch_bounds__(256) void smallmm2(const float* __restrict__ down_w,
                                                const float* __restrict__ up_w,
                                                float* __restrict__ wd,
                                                float* __restrict__ weff) {
  __shared__ float As[32][68];
  __shared__ float Bs[32][68];
  const int tid = threadIdx.x;
  const int tx = tid & 15, ty = tid >> 4;
  const int b0 = blockIdx.x * 64, a0 = blockIdx.y * 64;
  const int which = blockIdx.z >> 2, j = blockIdx.z & 3;
  const int jh = j >> 1, jl = j & 1;
  const float* src = which ? up_w : down_w;
  float acc[4][4];
  #pragma unroll
  for (int i = 0; i < 4; i++)
    #pragma unroll
    for (int k = 0; k < 4; k++) acc[i][k] = 0.f;

  for (int k0 = 0; k0 < 512; k0 += 32) {
    #pragma unroll
    for (int rep = 0; rep < 8; rep++) {
      int f = tid + rep * 256;
      int aa = f >> 5, mm = f & 31;
      size_t ai = which ? (524288 + (size_t)(k0 + mm) * 1024 + (a0 + aa) * 2 + jl)
                        : (524288 + (size_t)(a0 + aa) * 1024 + (k0 + mm) * 2 + jh);
      As[mm][aa] = src[ai];
      int mm2 = f >> 6, bb = f & 63;
      size_t bi = which ? ((size_t)(b0 + bb) * 1024 + (k0 + mm2) * 2 + jh)
                        : ((size_t)(k0 + mm2) * 1024 + (b0 + bb) * 2 + jl);
      Bs[mm2][bb] = src[bi];
    }
    __syncthreads();
    #pragma unroll
    for (int kk = 0; kk < 32; kk++) {
      float av[4], bv[4];
      #pragma unroll
      for (int i = 0; i < 4; i++) av[i] = As[kk][ty * 4 + i];
      #pragma unroll
      for (int i = 0; i < 4; i++) bv[i] = Bs[kk][tx * 4 + i];
      #pragma unroll
      for (int i = 0; i < 4; i++)
        #pragma unroll
        for (int k = 0; k < 4; k++) acc[i][k] = fmaf(av[i], bv[k], acc[i][k]);
    }
    __syncthreads();
  }
  #pragma unroll
  for (int i = 0; i < 4; i++) {
    int a = a0 + ty * 4 + i;
    #pragma unroll
    for (int k = 0; k < 4; k++) {
      int b = b0 + tx * 4 + k;
      if (which) weff[((size_t)a * 4 + j) * 512 + b] = acc[i][k];
      else       wd[(size_t)a * 2048 + b * 4 + j] = acc[i][k];
    }
  }
}

// ---------------- merged wdsplit (bid<4096) + prep_wx (bid>=4096) ----------------
__global__ __launch_bounds__(256) void prep_split_wx(const float* __restrict__ wd,
                                                     u16* __restrict__ wdp,
                                                     const float* __restrict__ weff,
                                                     const float* __restrict__ wouts,
                                                     float* __restrict__ wx) {
  const int tid = threadIdx.x;
  if (blockIdx.x < 4096) {
    int idx = blockIdx.x * 256 + tid;
    float v = wd[idx];
    unsigned u = __float_as_uint(v);
    wdp[idx] = (u16)(u >> 16);
    float r = v - __uint_as_float(u & 0xFFFF0000u);
    unsigned ur = __float_as_uint(r);
    wdp[APS + idx] = (u16)(ur >> 16);
    float r2 = r - __uint_as_float(ur & 0xFFFF0000u);
    wdp[2 * APS + idx] = (u16)(__float_as_uint(r2) >> 16);
    return;
  }
  __shared__ float Wes[16][512];
  __shared__ float WSs[64][80];
  const int m0 = (blockIdx.x - 4096) * 16;
  #pragma unroll
  for (int rep = 0; rep < 32; rep++) {
    int f = tid + rep * 256;
    Wes[f >> 9][f & 511] = weff[(size_t)(m0 + (f >> 9)) * 512 + (f & 511)];
  }
  const int rowq = tid >> 4, rq = tid & 15;
  float accs[5] = {0.f, 0.f, 0.f, 0.f, 0.f};
  for (int k0 = 0; k0 < 512; k0 += 64) {
    __syncthreads();
    #pragma unroll
    for (int rep = 0; rep < 20; rep++) {
      int f = tid + rep * 256;
      int kk = f / 80, col = f % 80;
      WSs[kk][col] = wouts[(size_t)(k0 + kk) * 80 + col];
    }
    __syncthreads();
    #pragma unroll 4
    for (int kk = 0; kk < 64; kk++) {
      float we = Wes[rowq][k0 + kk];
      #pragma unroll
      for (int s = 0; s < 5; s++) accs[s] = fmaf(we, WSs[kk][rq + 16 * s], accs[s]);
    }
  }
  #pragma unroll
  for (int s = 0; s < 5; s++) {
    int r = rq + 16 * s;
    if (r < 73) wx[(size_t)(m0 + rowq) * 80 + r] = accs[s];
  }
  if (tid < 112) {
    int row = tid / 7, col = 73 + tid % 7;
    wx[(size_t)(m0 + row) * 80 + col] = 0.f;
  }
}

// ---------------- gemm_down (R12 verbatim: 128x128, 4 waves, 277us) ----------------
__global__ __launch_bounds__(256) void gemm_down(const u16* __restrict__ Ap,
                                                 const float* __restrict__ z,
                                                 const float* __restrict__ bias,
                                                 float* __restrict__ Out) {
  constexpr int NS = 3, K = 2048;
  __shared__ u16 Bp[2][NS][128][32];
  const int tid = threadIdx.x;
  const int w = tid >> 6, l = tid & 63;
  const int g = l >> 4, li = l & 15;
  const int wr = w >> 1, wc = w & 1;
  const int n0 = blockIdx.x * 128, m0 = blockIdx.y * 128;
  const int nn = tid & 127, kw = tid >> 7;
  const int bb = n0 >> 11;
  const int tb = (n0 & 2047) + nn;

  f32x4 acc[4][4];
  #pragma unroll
  for (int a = 0; a < 4; a++)
    #pragma unroll
    for (int b = 0; b < 4; b++) acc[a][b] = (f32x4){0.f, 0.f, 0.f, 0.f};

  float pvA[16], pvB[16];

#define LOADB(PV, K0)                                                           \
  {                                                                             \
    int c0_ = ((K0) >> 2) + kw * 4;                                             \
    _Pragma("unroll")                                                           \
    for (int cc_ = 0; cc_ < 4; ++cc_)                                           \
      *(float4*)&PV[4 * cc_] =                                                  \
          *(const float4*)(z + ((size_t)(bb * 512 + c0_ + cc_) << 13) + 4 * tb);\
  }

  const int sw = (nn >> 1) & 3;
  const int c0 = ((2 * kw) ^ sw) << 3, c1 = ((2 * kw + 1) ^ sw) << 3;

#define STAGE(BUF, PV)                                                          \
  {                                                                             \
    su16x8 pa_[NS], pb_[NS];                                                    \
    _Pragma("unroll")                                                           \
    for (int j_ = 0; j_ < 8; ++j_) {                                            \
      {                                                                         \
        float v_ = PV[j_];                                                      \
        unsigned u_ = __float_as_uint(v_);                                      \
        pa_[0][j_] = (u16)(u_ >> 16);                                           \
        float r_ = v_ - __uint_as_float(u_ & 0xFFFF0000u);                      \
        unsigned ur_ = __float_as_uint(r_);                                     \
        pa_[1][j_] = (u16)(ur_ >> 16);                                          \
        float r2_ = r_ - __uint_as_float(ur_ & 0xFFFF0000u);                    \
        pa_[2][j_] = (u16)(__float_as_uint(r2_) >> 16);                         \
      }                                                                         \
      {                                                                         \
        float v_ = PV[8 + j_];                                                  \
        unsigned u_ = __float_as_uint(v_);                                      \
        pb_[0][j_] = (u16)(u_ >> 16);                                           \
        float r_ = v_ - __uint_as_float(u_ & 0xFFFF0000u);                      \
        unsigned ur_ = __float_as_uint(r_);                                     \
        pb_[1][j_] = (u16)(ur_ >> 16);                                          \
        float r2_ = r_ - __uint_as_float(ur_ & 0xFFFF0000u);                    \
        pb_[2][j_] = (u16)(__float_as_uint(r2_) >> 16);                         \
      }                                                                         \
    }                                                                           \
    _Pragma("unroll")                                                           \
    for (int p_ = 0; p_ < NS; ++p_) {                                           \
      *(su16x8*)&Bp[BUF][p_][nn][c0] = pa_[p_];                                 \
      *(su16x8*)&Bp[BUF][p_][nn][c1] = pb_[p_];                                 \
    }                                                                           \
  }

#define COMPUTE(BUF, K0)                                                        \
  {                                                                             \
    bf16x8 bfr_[4][NS];                                                         \
    _Pragma("unroll")                                                           \
    for (int fn_ = 0; fn_ < 4; ++fn_) {                                         \
      int row_ = wc * 64 + fn_ * 16 + li;                                       \
      int cs_ = ((g ^ ((row_ >> 1) & 3)) << 3);                                 \
      _Pragma("unroll")                                                         \
      for (int q_ = 0; q_ < NS; ++q_)                                           \
        bfr_[fn_][q_] = *(const bf16x8*)&Bp[BUF][q_][row_][cs_];                \
    }                                                                           \
    const u16* arow_ = Ap + (size_t)(m0 + wr * 64 + li) * K + (K0) + g * 8;     \
    _Pragma("unroll")                                                           \
    for (int fm_ = 0; fm_ < 4; ++fm_) {                                         \
      bf16x8 afr_[NS];                                                          \
      _Pragma("unroll")                                                         \
      for (int p_ = 0; p_ < NS; ++p_)                                           \
        afr_[p_] = *(const bf16x8*)(arow_ + (size_t)p_ * APS + (size_t)fm_ * 16 * K); \
      _Pragma("unroll")                                                         \
      for (int fn_ = 0; fn_ < 4; ++fn_) {                                       \
        f32x4 a_ = acc[fm_][fn_];                                               \
        a_ = __builtin_amdgcn_mfma_f32_16x16x32_bf16(afr_[2], bfr_[fn_][0], a_, 0, 0, 0); \
        a_ = __builtin_amdgcn_mfma_f32_16x16x32_bf16(afr_[1], bfr_[fn_][1], a_, 0, 0, 0); \
        a_ = __builtin_amdgcn_mfma_f32_16x16x32_bf16(afr_[0], bfr_[fn_][2], a_, 0, 0, 0); \
        a_ = __builtin_amdgcn_mfma_f32_16x16x32_bf16(afr_[1], bfr_[fn_][0], a_, 0, 0, 0); \
        a_ = __builtin_amdgcn_mfma_f32_16x16x32_bf16(afr_[0], bfr_[fn_][1], a_, 0, 0, 0); \
        a_ = __builtin_amdgcn_mfma_f32_16x16x32_bf16(afr_[0], bfr_[fn_][0], a_, 0, 0, 0); \
        acc[fm_][fn_] = a_;                                                     \
      }                                                                         \
    }                                                                           \
  }

  LOADB(pvA, 0)
  LOADB(pvB, 32)
  STAGE(0, pvA)
  LOADB(pvA, 64)
  __syncthreads();

  for (int k0 = 0; k0 < K; k0 += 64) {
    STAGE(1, pvB)
    if (k0 + 96 < K) { LOADB(pvB, k0 + 96) }
    COMPUTE(0, k0)
    __syncthreads();
    if (k0 + 64 < K) { STAGE(0, pvA) }
    if (k0 + 128 < K) { LOADB(pvA, k0 + 128) }
    COMPUTE(1, k0 + 32)
    __syncthreads();
  }
#undef LOADB
#undef STAGE
#undef COMPUTE

  const int mb = m0 + wr * 64 + g * 4;
  const int nb = n0 + wc * 64 + li;
  #pragma unroll
  for (int fn = 0; fn < 4; ++fn) {
    int n = nb + fn * 16;
    int b = n >> 11, t = n & 2047;
    #pragma unroll
    for (int fm = 0; fm < 4; ++fm)
      #pragma unroll
      for (int r = 0; r < 4; ++r) {
        int o = mb + fm * 16 + r;
        Out[((size_t)((b << 9) + o)) * 2048 + t] = acc[fm][fn][r] + bias[o];
      }
  }
}

// ---------------- gemm_e0f (R14 verbatim) ----------------
__global__ __launch_bounds__(256) void gemm_e0f(const float* __restrict__ A,
                                                const float* __restrict__ Bsrc,
                                                float* __restrict__ e0t) {
  constexpr int M = 72, K = 512, Tt = 2048;
  __shared__ float As[16][132];
  __shared__ float Bs[16][68];
  int tid = threadIdx.x;
  int tx = tid & 7, ty = tid >> 3;
  int n0 = blockIdx.x * 64;
  int b = n0 / Tt, t0 = n0 % Tt;
  float acc[4][8];
  #pragma unroll
  for (int i = 0; i < 4; i++)
    #pragma unroll
    for (int j = 0; j < 8; j++) acc[i][j] = 0.f;

  for (int k0 = 0; k0 < K; k0 += 16) {
    #pragma unroll
    for (int rep = 0; rep < 2; rep++) {
      int f = tid + rep * 256;
      int row = f >> 2, c4 = (f & 3) << 2;
      int m = row, k = k0 + c4;
      float4 v = make_float4(0.f, 0.f, 0.f, 0.f);
      if (m < M) v = *(const float4*)(A + (size_t)m * K + k);
      As[c4 + 0][row] = v.x; As[c4 + 1][row] = v.y;
      As[c4 + 2][row] = v.z; As[c4 + 3][row] = v.w;
    }
    {
      int kk = tid >> 4, n4 = (tid & 15) << 2;
      float4 v = *(const float4*)(Bsrc + ((size_t)(b * K + k0 + kk)) * Tt + t0 + n4);
      *(float4*)&Bs[kk][n4] = v;
    }
    __syncthreads();
    #pragma unroll
    for (int kk = 0; kk < 16; kk++) {
      float a[4], bb[8];
      #pragma unroll
      for (int i = 0; i < 4; i++) a[i] = As[kk][ty * 4 + i];
      *(float4*)&bb[0] = *(float4*)&Bs[kk][tx * 8];
      *(float4*)&bb[4] = *(float4*)&Bs[kk][tx * 8 + 4];
      #pragma unroll
      for (int i = 0; i < 4; i++)
        #pragma unroll
        for (int j = 0; j < 8; j++) acc[i][j] = fmaf(a[i], bb[j], acc[i][j]);
    }
    __syncthreads();
  }
  #pragma unroll
  for (int j = 0; j < 8; j++) {
    int n = n0 + tx * 8 + j;
    #pragma unroll
    for (int i = 0; i < 4; i++) {
      int m = ty * 4 + i;
      if (m < M) e0t[(size_t)n * M + m] = acc[i][j];
    }
  }
}

// ---------------- xfin: Q n-major [n][80]; contiguous staging ----------------
__global__ __launch_bounds__(256) void xfin(const float* __restrict__ wx,
                                            const float* __restrict__ Q,
                                            const float* __restrict__ bup,
                                            float* __restrict__ xout) {
  __shared__ float Wxs[128][80];
  __shared__ float Qs[128][80];
  const int tid = threadIdx.x;
  const int n0 = blockIdx.x * 128, m0 = blockIdx.y * 128;
  #pragma unroll
  for (int rep = 0; rep < 10; rep++) {
    int f = tid + rep * 256;
    *(float4*)&Wxs[0][f * 4] = *(const float4*)(wx + (size_t)m0 * 80 + f * 4);
    *(float4*)&Qs[0][f * 4] = *(const float4*)(Q + (size_t)n0 * 80 + f * 4);
  }
  __syncthreads();

  const int txn = tid & 15, tym = tid >> 4;
  float acc[8][8];
  #pragma unroll
  for (int i = 0; i < 8; i++)
    #pragma unroll
    for (int j = 0; j < 8; j++) acc[i][j] = 0.f;

  #pragma unroll 2
  for (int r4 = 0; r4 < 18; r4++) {
    float4 wv[8], qv[8];
    #pragma unroll
    for (int i = 0; i < 8; i++) wv[i] = *(const float4*)&Wxs[tym * 8 + i][r4 * 4];
    #pragma unroll
    for (int j = 0; j < 8; j++) qv[j] = *(const float4*)&Qs[txn * 8 + j][r4 * 4];
    #pragma unroll
    for (int i = 0; i < 8; i++)
      #pragma unroll
      for (int j = 0; j < 8; j++) {
        acc[i][j] = fmaf(wv[i].x, qv[j].x, acc[i][j]);
        acc[i][j] = fmaf(wv[i].y, qv[j].y, acc[i][j]);
        acc[i][j] = fmaf(wv[i].z, qv[j].z, acc[i][j]);
        acc[i][j] = fmaf(wv[i].w, qv[j].w, acc[i][j]);
      }
  }

  float bxv[8];
  #pragma unroll
  for (int mi = 0; mi < 8; mi++) {
    int mp = m0 + tym * 8 + mi;
    bxv[mi] = Wxs[tym * 8 + mi][72] + bup[(mp >> 2) * 2 + (mp & 1)];
  }
  #pragma unroll
  for (int cg = 0; cg < 2; cg++) {
    int mp0 = m0 + tym * 8 + cg * 4;
    int c = mp0 >> 2;
    #pragma unroll
    for (int j = 0; j < 8; j++) {
      int n = n0 + txn * 8 + j;
      int b = n >> 11, t = n & 2047;
      float4 sv = make_float4(acc[cg * 4 + 0][j] + bxv[cg * 4 + 0],
                              acc[cg * 4 + 1][j] + bxv[cg * 4 + 1],
                              acc[cg * 4 + 2][j] + bxv[cg * 4 + 2],
                              acc[cg * 4 + 3][j] + bxv[cg * 4 + 3]);
      *(float4*)&xout[((size_t)((b << 9) + c)) * 8192 + 4 * t] = sv;
    }
  }
}

// ---------------- RVQ core: Pt from global (bit-exact), Q n-major ----------------
__global__ __launch_bounds__(256) void rvq_kernel(const float* __restrict__ codebooks,
                                                  const float* __restrict__ e0t,
                                                  const float* __restrict__ cbsW,
                                                  const float* __restrict__ ptW,
                                                  const float* __restrict__ beffW,
                                                  float* __restrict__ Qout,
                                                  float* __restrict__ codesOut,
                                                  float* __restrict__ lossPart) {
  __shared__ float cbv[8][1024];
  __shared__ float cbs2[2][1024];
  __shared__ float est[16][72];
  __shared__ float lred[4];
  int tid = threadIdx.x, wid = tid >> 6, lane = tid & 63;
  int nb0 = blockIdx.x * 16;
  for (int idx = tid; idx < 16 * 72; idx += 256)
    est[idx / 72][idx % 72] = e0t[(size_t)nb0 * 72 + idx] + beffW[idx % 72];
  float lossLocal = 0.f;

  for (int i = 0; i < NQ; i++) {
    __syncthreads();
    const float* cbg = codebooks + (size_t)i * CBS * CBD;
    for (int lin = tid; lin < 2048; lin += 256) {
      int j = lin >> 1, half = (lin & 1) << 2;
      float4 v = *(const float4*)(cbg + (size_t)j * 8 + half);
      cbv[half + 0][j] = v.x; cbv[half + 1][j] = v.y;
      cbv[half + 2][j] = v.z; cbv[half + 3][j] = v.w;
    }
    for (int lin = tid; lin < 1024; lin += 256) {
      cbs2[0][lin] = cbsW[((size_t)i * 2 + 0) * 1024 + lin];
      cbs2[1][lin] = cbsW[((size_t)i * 2 + 1) * 1024 + lin];
    }
    __syncthreads();

    float ze[4][8], en[4][8];
    #pragma unroll
    for (int w = 0; w < 4; w++) {
      int tokl = wid * 4 + w;
      float ss = 0.f;
      #pragma unroll
      for (int d = 0; d < 8; d++) { float v = est[tokl][i * 8 + d]; ze[w][d] = v; ss += v * v; }
      float inv = 1.0f / fmaxf(sqrtf(ss), EPSN);
      #pragma unroll
      for (int d = 0; d < 8; d++) en[w][d] = ze[w][d] * inv;
    }
    float best[4]; int bidx[4];
    #pragma unroll
    for (int w = 0; w < 4; w++) { best[w] = -INFINITY; bidx[w] = 0; }
    #pragma unroll 4
    for (int r = 0; r < 16; r++) {
      int j = lane + (r << 6);
      float c0 = cbv[0][j], c1 = cbv[1][j], c2 = cbv[2][j], c3 = cbv[3][j];
      float c4 = cbv[4][j], c5 = cbv[5][j], c6 = cbv[6][j], c7 = cbv[7][j];
      float ti = cbs2[0][j], ns = cbs2[1][j];
      #pragma unroll
      for (int w = 0; w < 4; w++) {
        float dt = en[w][0] * c0;
        dt = fmaf(en[w][1], c1, dt); dt = fmaf(en[w][2], c2, dt);
        dt = fmaf(en[w][3], c3, dt); dt = fmaf(en[w][4], c4, dt);
        dt = fmaf(en[w][5], c5, dt); dt = fmaf(en[w][6], c6, dt);
        dt = fmaf(en[w][7], c7, dt);
        float s = fmaf(dt, ti, -ns);
        if (s > best[w]) { best[w] = s; bidx[w] = j; }
      }
    }
    #pragma unroll
    for (int w = 0; w < 4; w++) {
      #pragma unroll
      for (int off = 32; off; off >>= 1) {
        float so = __shfl_xor(best[w], off);
        int jo = __shfl_xor(bidx[w], off);
        if (so > best[w] || (so == best[w] && jo < bidx[w])) { best[w] = so; bidx[w] = jo; }
      }
    }
    int d = lane & 7;
    #pragma unroll
    for (int w = 0; w < 4; w++) {
      int jstar = bidx[w];
      int tokl = wid * 4 + w;
      int n = nb0 + tokl;
      float qd = cbv[d][jstar];
      float diff = ze[w][d] - qd;
      float sq = diff * diff;
      sq += __shfl_xor(sq, 1); sq += __shfl_xor(sq, 2); sq += __shfl_xor(sq, 4);
      if (lane == 0) lossLocal += sq;
      if (lane < 8) Qout[(size_t)n * 80 + i * 8 + lane] = qd;
      if (lane == 0) codesOut[(size_t)((n >> 11) * NQ + i) * TQ + (n & (TQ - 1))] = (float)jstar;
      if (i < NQ - 1) {
        int f = lane >> 3, d2 = lane & 7;
        int ip = i + 1 + f;
        if (ip < NQ) {
          int tri = (ip * (ip - 1)) / 2 + i;
          const float* prow = ptW + (size_t)tri * 65 + d2 * 8;
          float s = 0.f;
          #pragma unroll
          for (int dp = 0; dp < 8; dp++) s = fmaf(prow[dp], cbv[dp][jstar], s);
          est[tokl][ip * 8 + d2] -= s;
        }
      }
    }
  }
  if (lane == 0) lred[wid] = lossLocal;
  __syncthreads();
  if (tid == 0) {
    float s = ((lred[0] + lred[1]) + lred[2]) + lred[3];
    lossPart[blockIdx.x] = s;
  }
}

__global__ void loss_fin(const float* __restrict__ lossPart, float* __restrict__ out) {
  __shared__ float s[256];
  int tid = threadIdx.x;
  float v = 0.f;
  for (int r = 0; r < 4; r++) v += lossPart[tid + r * 256];
  s[tid] = v;
  __syncthreads();
  for (int w = 128; w; w >>= 1) {
    if (tid < w) s[tid] += s[tid + w];
    __syncthreads();
  }
  if (tid == 0) {
    float total = s[0] / 131072.0f;
    out[0] = total;
    out[1] = total;
  }
}

// ---------------- launch ----------------
extern "C" void kernel_launch(void* const* d_in, const int* in_sizes, int n_in,
                              void* d_out, int out_size, void* d_ws, size_t ws_size,
                              hipStream_t stream) {
  const float* z      = (const float*)d_in[0];
  const float* down_w = (const float*)d_in[1];
  const float* down_b = (const float*)d_in[2];
  const float* up_w   = (const float*)d_in[3];
  const float* up_b   = (const float*)d_in[4];
  const float* in_v   = (const float*)d_in[5];
  const float* in_g   = (const float*)d_in[6];
  const float* in_b   = (const float*)d_in[7];
  const float* out_v  = (const float*)d_in[8];
  const float* out_g  = (const float*)d_in[9];
  const float* out_b  = (const float*)d_in[10];
  const float* codebooks = (const float*)d_in[11];
  float* ws = (float*)d_ws;
  float* xout = (float*)d_out;
  float* codesOut = xout + (size_t)8 * 512 * 8192;
  float* lossOut = codesOut + (size_t)8 * NQ * TQ;

  hipLaunchKernelGGL(prep_small1, dim3(206), dim3(256), 0, stream,
                     in_v, in_g, out_v, out_g, out_b, codebooks,
                     down_w, down_b, up_w, up_b, ws);
  hipLaunchKernelGGL(prep2, dim3(594), dim3(256), 0, stream, in_b, out_b, ws);
  hipLaunchKernelGGL(smallmm2, dim3(8, 8, 8), dim3(256), 0, stream,
                     down_w, up_w, ws + OFF_WD, ws + OFF_WEFF);
  hipLaunchKernelGGL(prep_split_wx, dim3(4224), dim3(256), 0, stream,
                     ws + OFF_WD, (u16*)(ws + OFF_WDP),
                     ws + OFF_WEFF, ws + OFF_WOUTS, ws + OFF_WX);
  // fused down: x2 = W_d(3-split) @ zg + b_d
  hipLaunchKernelGGL(gemm_down, dim3(128, 4), dim3(256), 0, stream,
                     (const u16*)(ws + OFF_WDP), z, ws + OFF_BD, ws + OFF_X2);
  // e0t = WinN @ x2
  hipLaunchKernelGGL(gemm_e0f, dim3(256), dim3(256), 0, stream,
                     ws + OFF_WINN, ws + OFF_X2, ws + OFF_E0T);
  // RVQ
  hipLaunchKernelGGL(rvq_kernel, dim3(1024), dim3(256), 0, stream,
                     codebooks, ws + OFF_E0T, ws + OFF_CBS, ws + OFF_PT, ws + OFF_BEFF,
                     ws + OFF_Q, codesOut, ws + OFF_LOSS);
  // x = Wx @ Q + bx
  hipLaunchKernelGGL(xfin, dim3(128, 16), dim3(256), 0, stream,
                     ws + OFF_WX, ws + OFF_Q, ws + OFF_BUP, xout);
  hipLaunchKernelGGL(loss_fin, dim3(1), dim3(256), 0, stream, ws + OFF_LOSS, lossOut);
}